// Round 12
// baseline (381.533 us; speedup 1.0000x reference)
//
#include <hip/hip_runtime.h>
#include <hip/hip_bf16.h>
#include <stdint.h>
#include <stddef.h>

// Problem constants (fixed by the reference)
constexpr int BATCH = 2;
constexpr int SEQ   = 2048;
constexpr int EMBD  = 2048;
constexpr int NHEAD = 16;
constexpr int HDIM  = 128;
// 1/sqrt(128) * log2(e): scores land in log2-domain -> exp2 directly
constexpr float QSCALE = 0.08838834764831845f * 1.4426950408889634f;

typedef short bf16x8 __attribute__((ext_vector_type(8)));
typedef float f32x4  __attribute__((ext_vector_type(4)));

__device__ __forceinline__ short f2bfs(float f) {
  union { __hip_bfloat16 h; short s; } u;
  u.h = __float2bfloat16(f);   // hardware cvt (RNE), pairs fuse to v_cvt_pk_bf16_f32
  return u.s;
}

__device__ __forceinline__ void gload_lds16(const void* g, void* l) {
  __builtin_amdgcn_global_load_lds(
      (const __attribute__((address_space(1))) unsigned int*)g,
      (__attribute__((address_space(3))) unsigned int*)l, 16, 0, 0);
}

// key index -> position within vti's interleaved row (16B slot holds keys
// {32c+4g..+3, 32c+16+4g..+3} so PV A-frags are single b128 reads)
__device__ __forceinline__ int vperm(int k) {
  return (k & ~31) | (k & 3) | (((k >> 4) & 1) << 2) | (((k >> 2) & 3) << 3);
}

// ---------------------------------------------------------------------------
// fp32 -> bf16 cast, all three tensors in one launch (G13 vectorized)
// ---------------------------------------------------------------------------
__global__ void cvt_bf16_3(const float* __restrict__ s0, unsigned short* __restrict__ d0, int n0,
                           const float* __restrict__ s1, unsigned short* __restrict__ d1, int n1,
                           const float* __restrict__ s2, unsigned short* __restrict__ d2, int n2) {
  int i = (blockIdx.x * blockDim.x + threadIdx.x) * 8;
  const int stride = gridDim.x * blockDim.x * 8;
  const int t01 = n0 + n1, tot = n0 + n1 + n2;
  for (; i < tot; i += stride) {
    const float* s; unsigned short* d; int off;
    if (i < n0)      { s = s0; d = d0; off = i; }
    else if (i < t01){ s = s1; d = d1; off = i - n0; }
    else             { s = s2; d = d2; off = i - t01; }
    float4 a = *(const float4*)(s + off);
    float4 b = *(const float4*)(s + off + 4);
    union { unsigned short u[8]; int4 v; } r;
    r.u[0] = (unsigned short)f2bfs(a.x); r.u[1] = (unsigned short)f2bfs(a.y);
    r.u[2] = (unsigned short)f2bfs(a.z); r.u[3] = (unsigned short)f2bfs(a.w);
    r.u[4] = (unsigned short)f2bfs(b.x); r.u[5] = (unsigned short)f2bfs(b.y);
    r.u[6] = (unsigned short)f2bfs(b.z); r.u[7] = (unsigned short)f2bfs(b.w);
    *(int4*)(d + off) = r.v;
  }
}

// ---------------------------------------------------------------------------
// Epilogues
// ---------------------------------------------------------------------------
struct EpiQKV {
  const float* bias;
  unsigned short* qs; unsigned short* ks; unsigned short* vti;
  __device__ void operator()(int row, int col, float v) const {
    float val = v + bias[col];
    const int which = col >> 11;          // 0:q 1:k 2:v  (block-uniform)
    const int h = (col >> 7) & 15;
    const int d = col & 127;
    const int b = row >> 11, l = row & (SEQ - 1);
    if (which == 0) {
      qs[(((unsigned)(b * NHEAD + h) * SEQ) + l) * HDIM + d] = (unsigned short)f2bfs(val * QSCALE);
    } else if (which == 1) {
      ks[(((unsigned)(b * NHEAD + h) * SEQ) + l) * HDIM + d] = (unsigned short)f2bfs(val);
    } else {
      // V stored pre-transposed + key-interleaved: [B,H,D,SEQperm]
      vti[(((unsigned)(b * NHEAD + h) * HDIM) + d) * SEQ + vperm(l)] = (unsigned short)f2bfs(val);
    }
  }
};

struct EpiOut {
  const float* bias;
  float* out;
  __device__ void operator()(int row, int col, float v) const {
    out[(size_t)row * EMBD + col] = v + bias[col];
  }
};

// ---------------------------------------------------------------------------
// gemm1 (QKV): 256x256 tile, BK=64, 8 waves, 8-phase staggered schedule
// (round-10 measured-best: 150.2 us, FETCH 94 MB, conflicts 0).
// ---------------------------------------------------------------------------
__global__ __launch_bounds__(512, 2) void gemm_qkv8(
    const unsigned short* __restrict__ A, const unsigned short* __restrict__ B,
    EpiQKV epi) {
  __shared__ __align__(16) unsigned short lds[2][32768];
  const int tid = threadIdx.x, w = tid >> 6, lane = tid & 63;
  const int g = lane >> 4, lr = lane & 15;
  const int wm = w >> 2, wn = w & 3;
  const int m0 = ((int)blockIdx.x / 24) * 256;
  const int n0 = ((int)blockIdx.x % 24) * 256;
  constexpr int K = 2048;
  constexpr int nt = K / 64;   // 32

  const int srow = tid >> 3, sslot = tid & 7;

  auto stageH = [&](int t, int sel, int hh) {
    const unsigned short* src = sel ? B : A;
    const int base0 = sel ? n0 : m0;
    const int kel = t * 64 + ((sslot ^ (srow & 7)) << 3);
#pragma unroll
    for (int l = 0; l < 2; ++l)
      gload_lds16(src + (size_t)(base0 + hh * 128 + l * 64 + srow) * K + kel,
                  &lds[t & 1][sel * 16384 + hh * 8192 + (l * 512 + tid) * 8]);
  };
  auto rdA = [&](int buf, int Mh, int kk, int fr) -> bf16x8 {
    const int r = Mh * 128 + wm * 64 + fr * 16 + lr;
    return *(const bf16x8*)&lds[buf][r * 64 + (((kk * 4 + g) ^ (r & 7)) << 3)];
  };
  auto rdB = [&](int buf, int Nh, int kk, int fb) -> bf16x8 {
    const int r = Nh * 128 + wn * 32 + fb * 16 + lr;
    return *(const bf16x8*)&lds[buf][16384 + r * 64 + (((kk * 4 + g) ^ (r & 7)) << 3)];
  };

  f32x4 acc[8][4] = {};            // [Mh*4+fr][Nh*2+fb]
  bf16x8 a[4][2], bl[2][2], bh[2][2];

  // prologue: tile 0 fully + tile 1 {A-lo, B-lo, B-hi}
  stageH(0, 0, 0); stageH(0, 0, 1); stageH(0, 1, 0); stageH(0, 1, 1);
  stageH(1, 0, 0); stageH(1, 1, 0); stageH(1, 1, 1);
  asm volatile("s_waitcnt vmcnt(6)" ::: "memory");   // tile 0 landed
  __builtin_amdgcn_s_barrier();

  for (int t = 0; t < nt; ++t) {
    const int buf = t & 1;
    // ---- phase 1: (M0,N0); read A-lo + B-lo; stage t+1.A-hi (other buf)
#pragma unroll
    for (int fr = 0; fr < 4; ++fr) { a[fr][0] = rdA(buf, 0, 0, fr); a[fr][1] = rdA(buf, 0, 1, fr); }
#pragma unroll
    for (int fb = 0; fb < 2; ++fb) { bl[fb][0] = rdB(buf, 0, 0, fb); bl[fb][1] = rdB(buf, 0, 1, fb); }
    if (t + 1 < nt) stageH(t + 1, 0, 1);
    __builtin_amdgcn_s_barrier();
    asm volatile("s_waitcnt lgkmcnt(0)" ::: "memory");
    __builtin_amdgcn_s_setprio(1);
#pragma unroll
    for (int fr = 0; fr < 4; ++fr)
#pragma unroll
      for (int fb = 0; fb < 2; ++fb)
#pragma unroll
        for (int kk = 0; kk < 2; ++kk)
          acc[fr][fb] = __builtin_amdgcn_mfma_f32_16x16x32_bf16(a[fr][kk], bl[fb][kk], acc[fr][fb], 0, 0, 0);
    __builtin_amdgcn_s_setprio(0);
    __builtin_amdgcn_s_barrier();
    // ---- phase 2: (M0,N1); read B-hi; stage t+2.A-lo (current buf, dead)
#pragma unroll
    for (int fb = 0; fb < 2; ++fb) { bh[fb][0] = rdB(buf, 1, 0, fb); bh[fb][1] = rdB(buf, 1, 1, fb); }
    if (t + 2 < nt) stageH(t + 2, 0, 0);
    __builtin_amdgcn_s_barrier();
    asm volatile("s_waitcnt lgkmcnt(0)" ::: "memory");
    __builtin_amdgcn_s_setprio(1);
#pragma unroll
    for (int fr = 0; fr < 4; ++fr)
#pragma unroll
      for (int fb = 0; fb < 2; ++fb)
#pragma unroll
        for (int kk = 0; kk < 2; ++kk)
          acc[fr][2 + fb] = __builtin_amdgcn_mfma_f32_16x16x32_bf16(a[fr][kk], bh[fb][kk], acc[fr][2 + fb], 0, 0, 0);
    __builtin_amdgcn_s_setprio(0);
    __builtin_amdgcn_s_barrier();
    // ---- phase 3: (M1,N1); read A-hi; stage t+2.B-lo (dead since p1)
#pragma unroll
    for (int fr = 0; fr < 4; ++fr) { a[fr][0] = rdA(buf, 1, 0, fr); a[fr][1] = rdA(buf, 1, 1, fr); }
    if (t + 2 < nt) stageH(t + 2, 1, 0);
    __builtin_amdgcn_s_barrier();
    asm volatile("s_waitcnt lgkmcnt(0)" ::: "memory");
    __builtin_amdgcn_s_setprio(1);
#pragma unroll
    for (int fr = 0; fr < 4; ++fr)
#pragma unroll
      for (int fb = 0; fb < 2; ++fb)
#pragma unroll
        for (int kk = 0; kk < 2; ++kk)
          acc[4 + fr][2 + fb] = __builtin_amdgcn_mfma_f32_16x16x32_bf16(a[fr][kk], bh[fb][kk], acc[4 + fr][2 + fb], 0, 0, 0);
    __builtin_amdgcn_s_setprio(0);
    __builtin_amdgcn_s_barrier();
    // ---- phase 4: (M1,N0); no reads (A-hi + B-lo in regs); stage t+2.B-hi
    if (t + 2 < nt) stageH(t + 2, 1, 1);
    __builtin_amdgcn_s_barrier();
    __builtin_amdgcn_s_setprio(1);
#pragma unroll
    for (int fr = 0; fr < 4; ++fr)
#pragma unroll
      for (int fb = 0; fb < 2; ++fb)
#pragma unroll
        for (int kk = 0; kk < 2; ++kk)
          acc[4 + fr][fb] = __builtin_amdgcn_mfma_f32_16x16x32_bf16(a[fr][kk], bl[fb][kk], acc[4 + fr][fb], 0, 0, 0);
    __builtin_amdgcn_s_setprio(0);
    // ---- K-tile boundary: counted vmcnt proves tile t+1 fully landed
    if (t + 2 < nt) {
      asm volatile("s_waitcnt vmcnt(6)" ::: "memory");
    } else if (t + 1 < nt) {
      asm volatile("s_waitcnt vmcnt(0)" ::: "memory");
    }
    __builtin_amdgcn_s_barrier();
  }

  // epilogue: interleaved-quadrant positions
#pragma unroll
  for (int mf = 0; mf < 8; ++mf)
#pragma unroll
    for (int nf = 0; nf < 4; ++nf) {
      const int row = m0 + (mf >> 2) * 128 + wm * 64 + (mf & 3) * 16 + g * 4;
      const int col = n0 + (nf >> 1) * 128 + wn * 32 + (nf & 1) * 16 + lr;
#pragma unroll
      for (int jr = 0; jr < 4; ++jr) epi(row + jr, col, acc[mf][nf][jr]);
    }
}

// ---------------------------------------------------------------------------
// GEMM body (m97 structure, 128x128 tile, BK=32) — kept for the output GEMM
// ---------------------------------------------------------------------------
template <class Epi>
__device__ void gemm_body(unsigned short* ldsbuf,
                          const unsigned short* __restrict__ A,
                          const unsigned short* __restrict__ B,
                          int K, int m0, int n0, Epi epi) {
  const int tid = threadIdx.x;
  const int w = tid >> 6, lane = tid & 63;
  const int g = lane >> 4, lr = lane & 15;
  const int wm = w >> 1, wn = w & 1;
  const int srow = lane >> 2, sslot = lane & 3;

  f32x4 acc[4][4] = {};

  auto stage = [&](int buf, int t) {
    const int k0 = t * 32;
    unsigned short* slot = ldsbuf + buf * 8192;
#pragma unroll
    for (int c2 = 0; c2 < 2; ++c2) {
      const int chunk = 2 * w + c2;
      const int row = chunk * 16 + srow;
      const int kel = k0 + ((sslot ^ ((row >> 1) & 3)) << 3);
      gload_lds16(A + (size_t)(m0 + row) * K + kel, &slot[chunk * 512]);
      gload_lds16(B + (size_t)(n0 + row) * K + kel, &slot[4096 + chunk * 512]);
    }
  };

  const int nt = K >> 5;
  int cur = 0;
  stage(0, 0);
  asm volatile("s_waitcnt vmcnt(0)" ::: "memory");
  __syncthreads();

  for (int t = 0; t < nt; ++t) {
    if (t + 1 < nt) stage(cur ^ 1, t + 1);
    const unsigned short* slot = ldsbuf + cur * 8192;
    bf16x8 af[4], bq[4];
#pragma unroll
    for (int fr = 0; fr < 4; ++fr) {
      const int r = wm * 64 + fr * 16 + lr;
      af[fr] = *(const bf16x8*)&slot[r * 32 + ((g ^ ((r >> 1) & 3)) << 3)];
      const int rn = wn * 64 + fr * 16 + lr;
      bq[fr] = *(const bf16x8*)&slot[4096 + rn * 32 + ((g ^ ((rn >> 1) & 3)) << 3)];
    }
#pragma unroll
    for (int i = 0; i < 4; ++i)
#pragma unroll
      for (int j = 0; j < 4; ++j)
        acc[i][j] = __builtin_amdgcn_mfma_f32_16x16x32_bf16(af[i], bq[j], acc[i][j], 0, 0, 0);
    asm volatile("s_waitcnt vmcnt(0)" ::: "memory");
    __syncthreads();
    cur ^= 1;
  }

#pragma unroll
  for (int i = 0; i < 4; ++i)
#pragma unroll
    for (int j = 0; j < 4; ++j) {
      const int row = m0 + wm * 64 + i * 16 + g * 4;
      const int col = n0 + wn * 64 + j * 16 + lr;
#pragma unroll
      for (int jr = 0; jr < 4; ++jr) epi(row + jr, col, acc[i][j][jr]);
    }
}

// ---------------------------------------------------------------------------
// attn_avg body: grouped-GEMM over heads with ring-3 LDS + counted vmcnt.
// ---------------------------------------------------------------------------
__device__ void attn_avg_body(unsigned short* lds,
                              const unsigned short* __restrict__ qs,
                              const unsigned short* __restrict__ ks,
                              const float* __restrict__ c_s,
                              float* __restrict__ out, int blk) {
  const int tid = threadIdx.x, w = tid >> 6, lane = tid & 63;
  const int g = lane >> 4, lr = lane & 15;
  const int wm = w >> 1, wn = w & 1;
  const int k0 = (blk & 15) * 128, q0 = ((blk >> 4) & 15) * 128, b = blk >> 8;
  const int srow = lane >> 2, sslot = lane & 3;

  constexpr int NC = NHEAD * 4;   // 64 chunks

  auto stage = [&](int c) {
    const size_t bh = ((size_t)(b * NHEAD + (c >> 2))) * SEQ * HDIM + (c & 3) * 32;
    unsigned short* slot = lds + (c % 3) * 8192;
#pragma unroll
    for (int c2 = 0; c2 < 2; ++c2) {
      const int chunk = 2 * w + c2;            // 0..7, 16 rows each
      const int row = chunk * 16 + srow;
      const int kel = (sslot ^ ((row >> 1) & 3)) << 3;
      gload_lds16(qs + bh + (size_t)(q0 + row) * HDIM + kel, &slot[chunk * 512]);
      gload_lds16(ks + bh + (size_t)(k0 + row) * HDIM + kel, &slot[4096 + chunk * 512]);
    }
  };

  f32x4 acc[4][4] = {};

  stage(0); stage(1);
  asm volatile("s_waitcnt vmcnt(4)" ::: "memory");
  asm volatile("s_barrier" ::: "memory");

  for (int hc = 0; hc < NHEAD; ++hc) {
    f32x4 st[4][4] = {};
#pragma unroll
    for (int dq = 0; dq < 4; ++dq) {
      const int c = hc * 4 + dq;
      if (c + 2 < NC) stage(c + 2);
      const unsigned short* slot = lds + (c % 3) * 8192;
      bf16x8 af[4], bq[4];
#pragma unroll
      for (int fr = 0; fr < 4; ++fr) {
        const int rq = wm * 64 + fr * 16 + lr;
        af[fr] = *(const bf16x8*)&slot[rq * 32 + ((g ^ ((rq >> 1) & 3)) << 3)];
        const int rk = wn * 64 + fr * 16 + lr;
        bq[fr] = *(const bf16x8*)&slot[4096 + rk * 32 + ((g ^ ((rk >> 1) & 3)) << 3)];
      }
#pragma unroll
      for (int i = 0; i < 4; ++i)
#pragma unroll
        for (int j = 0; j < 4; ++j)
          st[i][j] = __builtin_amdgcn_mfma_f32_16x16x32_bf16(af[i], bq[j], st[i][j], 0, 0, 0);
      if (c + 2 < NC) {
        asm volatile("s_waitcnt vmcnt(4)" ::: "memory");
        asm volatile("s_barrier" ::: "memory");
      } else if (c + 1 < NC) {
        asm volatile("s_waitcnt vmcnt(0)" ::: "memory");
        asm volatile("s_barrier" ::: "memory");
      }
    }
    const int chq = (b * NHEAD + hc) * SEQ + q0 + wm * 64 + g * 4;
#pragma unroll
    for (int i = 0; i < 4; ++i) {
      const f32x4 cq = *(const f32x4*)&c_s[chq + i * 16];
#pragma unroll
      for (int j = 0; j < 4; ++j)
#pragma unroll
        for (int jr = 0; jr < 4; ++jr)
          acc[i][j][jr] += __builtin_exp2f(st[i][j][jr] - cq[jr]);
    }
  }

#pragma unroll
  for (int i = 0; i < 4; ++i)
#pragma unroll
    for (int jr = 0; jr < 4; ++jr) {
      const size_t rowoff = (size_t)(b * SEQ + q0 + wm * 64 + i * 16 + g * 4 + jr) * SEQ;
#pragma unroll
      for (int j = 0; j < 4; ++j)
        out[rowoff + k0 + wn * 64 + j * 16 + lr] = acc[i][j][jr];
    }
}

// ---------------------------------------------------------------------------
// Fused tail, INTERLEAVED: even ids = output-GEMM tiles, odd = attn_avg.
// Pairs an MFMA-dense gemm2 block with an exp2/VALU-phased attn_avg block on
// each CU (m114 separate-pipe overlap) and balances the final round.
// ---------------------------------------------------------------------------
__global__ __launch_bounds__(256, 2) void tail_fused(
    const unsigned short* __restrict__ ctx, const unsigned short* __restrict__ wo,
    const float* __restrict__ b_out, float* __restrict__ out,
    const unsigned short* __restrict__ qs, const unsigned short* __restrict__ ks,
    const float* __restrict__ c_s, float* __restrict__ attn_avg) {
  __shared__ __align__(16) unsigned short lds[3 * 8192];
  const int id = blockIdx.x;
  const int sub = id >> 1;
  if (!(id & 1)) {
    gemm_body(lds, ctx, wo, EMBD, (sub >> 4) * 128, (sub & 15) * 128, EpiOut{b_out, out});
  } else {
    attn_avg_body(lds, qs, ks, c_s, attn_avg, sub);
  }
}

// ---------------------------------------------------------------------------
// Flash attention fwd v3 (round-8 proven). Grid: B*H*(SEQ/128) = 512 x 512thr.
// ---------------------------------------------------------------------------
__global__ __launch_bounds__(512, 4) void flash_fwd(
    const unsigned short* __restrict__ qs, const unsigned short* __restrict__ ks,
    const unsigned short* __restrict__ vti, unsigned short* __restrict__ ctx,
    float* __restrict__ c_s) {
  __shared__ __align__(16) unsigned short smem[32768];  // 2 bufs x (K 16KB + V^T 16KB)
  const int tid = threadIdx.x, w = tid >> 6, lane = tid & 63;
  const int g = lane >> 4, lr = lane & 15;
  const int blk = ((int)blockIdx.x & 7) * ((int)gridDim.x >> 3) + ((int)blockIdx.x >> 3);
  const int qt = blk & 15, h = (blk >> 4) & 15, b = blk >> 8;
  const int q0 = qt * 128;
  const size_t bh = ((size_t)(b * NHEAD + h)) * SEQ * HDIM;

  const int qrow = q0 + w * 16 + lr;
  bf16x8 qf[4];
#pragma unroll
  for (int kk = 0; kk < 4; ++kk)
    qf[kk] = *(const bf16x8*)(qs + bh + (size_t)qrow * HDIM + kk * 32 + g * 8);

  float m_run = -1e30f, l_run = 0.f;
  f32x4 o[8] = {};

  auto stage = [&](int buf, int t) {
    unsigned short* kt = smem + buf * 16384;
    unsigned short* vt = kt + 8192;
    const int key0 = t * 64;
#pragma unroll
    for (int c = 0; c < 2; ++c) {
      const int chunk = w * 2 + c;
      const int key = chunk * 4 + (lane >> 4);
      const int slot = lane & 15;
      gload_lds16(ks + bh + (size_t)(key0 + key) * HDIM + ((slot ^ (key & 7)) * 8),
                  &kt[chunk * 512]);
    }
#pragma unroll
    for (int c = 0; c < 2; ++c) {
      const int chunk = w * 2 + c;
      const int d = chunk * 8 + (lane >> 3);
      const int slot = lane & 7;
      gload_lds16(vti + bh + (size_t)d * SEQ + key0 + ((slot ^ (d & 7)) * 8),
                  &vt[chunk * 512]);
    }
  };

  stage(0, 0);
  asm volatile("s_waitcnt vmcnt(0)" ::: "memory");
  __syncthreads();
  int cur = 0;

  for (int t = 0; t < 32; ++t) {
    if (t + 1 < 32) stage(cur ^ 1, t + 1);
    const unsigned short* kt = smem + cur * 16384;
    const unsigned short* vt = kt + 8192;

    f32x4 st[4] = {};
    __builtin_amdgcn_s_setprio(1);
#pragma unroll
    for (int kk = 0; kk < 4; ++kk)
#pragma unroll
      for (int fc = 0; fc < 4; ++fc) {
        const int key = fc * 16 + lr;
        bf16x8 kf = *(const bf16x8*)&kt[key * 128 + (((kk * 4 + g) ^ (key & 7)) << 3)];
        st[fc] = __builtin_amdgcn_mfma_f32_16x16x32_bf16(kf, qf[kk], st[fc], 0, 0, 0);
      }
    __builtin_amdgcn_s_setprio(0);

    float tmax = st[0][0];
#pragma unroll
    for (int fc = 0; fc < 4; ++fc)
#pragma unroll
      for (int j = 0; j < 4; ++j) tmax = fmaxf(tmax, st[fc][j]);
    tmax = fmaxf(tmax, __shfl_xor(tmax, 16));
    tmax = fmaxf(tmax, __shfl_xor(tmax, 32));
    if (!__all(tmax <= m_run + 8.f)) {
      const float m_new = fmaxf(m_run, tmax);
      const float corr = __builtin_exp2f(m_run - m_new);
      l_run *= corr;
#pragma unroll
      for (int fd = 0; fd < 8; ++fd)
#pragma unroll
        for (int j = 0; j < 4; ++j) o[fd][j] *= corr;
      m_run = m_new;
    }
    float pt[4][4];
    float tsum = 0.f;
#pragma unroll
    for (int fc = 0; fc < 4; ++fc)
#pragma unroll
      for (int j = 0; j < 4; ++j) {
        const float e = __builtin_exp2f(st[fc][j] - m_run);
        pt[fc][j] = e; tsum += e;
      }
    tsum += __shfl_xor(tsum, 16);
    tsum += __shfl_xor(tsum, 32);
    l_run += tsum;

    bf16x8 pb[2];
#pragma unroll
    for (int c = 0; c < 2; ++c)
#pragma unroll
      for (int j = 0; j < 4; ++j) {
        pb[c][j]     = f2bfs(pt[2 * c][j]);
        pb[c][4 + j] = f2bfs(pt[2 * c + 1][j]);
      }

    __builtin_amdgcn_s_setprio(1);
#pragma unroll
    for (int fd = 0; fd < 8; ++fd) {
      const int d = fd * 16 + lr;
#pragma unroll
      for (int c = 0; c < 2; ++c) {
        bf16x8 vf = *(const bf16x8*)&vt[d * 64 + (((c * 4 + g) ^ (d & 7)) << 3)];
        o[fd] = __builtin_amdgcn_mfma_f32_16x16x32_bf16(vf, pb[c], o[fd], 0, 0, 0);
      }
    }
    __builtin_amdgcn_s_setprio(0);

    asm volatile("s_waitcnt vmcnt(0)" ::: "memory");
    __syncthreads();
    cur ^= 1;
  }

  const float inv_l = 1.0f / l_run;
  unsigned short* trp = smem + w * 2176;
#pragma unroll
  for (int fd = 0; fd < 8; ++fd)
#pragma unroll
    for (int jp = 0; jp < 2; ++jp) {
      const int d = fd * 16 + 4 * g + 2 * jp;
      unsigned valu = (unsigned)(unsigned short)f2bfs(o[fd][2 * jp] * inv_l) |
                      ((unsigned)(unsigned short)f2bfs(o[fd][2 * jp + 1] * inv_l) << 16);
      *(unsigned*)((char*)trp + lr * 272 + d * 2) = valu;
    }
  __syncthreads();
#pragma unroll
  for (int r4 = 0; r4 < 4; ++r4) {
    const int row = r4 * 4 + g;
    bf16x8 valv = *(const bf16x8*)((char*)trp + row * 272 + lr * 16);
    *(bf16x8*)(ctx + (size_t)(b * SEQ + q0 + w * 16 + row) * EMBD + h * HDIM + lr * 8) = valv;
  }
  if (g == 0) {
    const int ridx = (b * NHEAD + h) * SEQ + q0 + w * 16 + lr;
    c_s[ridx] = m_run + __log2f(l_run) + 4.0f;
  }
}

// ---------------------------------------------------------------------------
extern "C" void kernel_launch(void* const* d_in, const int* in_sizes, int n_in,
                              void* d_out, int out_size, void* d_ws, size_t ws_size,
                              hipStream_t stream) {
  const float* query = (const float*)d_in[0];
  // d_in[1] (key), d_in[2] (value) are ignored by the reference module
  const float* W_in  = (const float*)d_in[3];
  const float* b_in  = (const float*)d_in[4];
  const float* W_out = (const float*)d_in[5];
  const float* b_out = (const float*)d_in[6];

  float* out      = (float*)d_out;                       // [B,L,E]
  float* attn_avg = out + (size_t)BATCH * SEQ * EMBD;    // [B,L,L]

  char* ws = (char*)d_ws;
  auto take = [&](size_t bytes) { char* p = ws; ws += bytes; return p; };
  const size_t szBLE = (size_t)BATCH * SEQ * EMBD * 2;   // bf16 [B*L, E]
  unsigned short* qbf = (unsigned short*)take(szBLE);
  unsigned short* wi  = (unsigned short*)take((size_t)3 * EMBD * EMBD * 2);
  unsigned short* wo  = (unsigned short*)take((size_t)EMBD * EMBD * 2);
  unsigned short* qsb = (unsigned short*)take(szBLE);    // [B,H,L,D] *QSCALE
  unsigned short* ksb = (unsigned short*)take(szBLE);    // [B,H,L,D]
  unsigned short* vti = (unsigned short*)take(szBLE);    // [B,H,D,Lperm]
  unsigned short* ctx = (unsigned short*)take(szBLE);    // [B,L,H,D] == [B*L, E]
  float* c_s = (float*)take((size_t)BATCH * NHEAD * SEQ * 4);

  cvt_bf16_3<<<2048, 256, 0, stream>>>(query, qbf, BATCH * SEQ * EMBD,
                                       W_in, wi, 3 * EMBD * EMBD,
                                       W_out, wo, EMBD * EMBD);

  // qkv = query @ W_in^T + b_in  (M=4096, N=6144, K=2048), 8-phase 256^2
  gemm_qkv8<<<16 * 24, 512, 0, stream>>>(qbf, wi, EpiQKV{b_in, qsb, ksb, vti});
  // attention (writes ctx, c_s)
  flash_fwd<<<BATCH * NHEAD * (SEQ / 128), 512, 0, stream>>>(qsb, ksb, vti, ctx, c_s);
  // fused tail, interleaved: output GEMM (even) + attn_avg (odd)
  tail_fused<<<1024, 256, 0, stream>>>(ctx, wo, b_out, out, qsb, ksb, c_s, attn_avg);
}

// Round 13
// 369.225 us; speedup vs baseline: 1.0333x; 1.0333x over previous
//
#include <hip/hip_runtime.h>
#include <hip/hip_bf16.h>
#include <stdint.h>
#include <stddef.h>

// Problem constants (fixed by the reference)
constexpr int BATCH = 2;
constexpr int SEQ   = 2048;
constexpr int EMBD  = 2048;
constexpr int NHEAD = 16;
constexpr int HDIM  = 128;
// 1/sqrt(128) * log2(e): scores land in log2-domain -> exp2 directly
constexpr float QSCALE = 0.08838834764831845f * 1.4426950408889634f;

typedef short bf16x8 __attribute__((ext_vector_type(8)));
typedef float f32x4  __attribute__((ext_vector_type(4)));

__device__ __forceinline__ short f2bfs(float f) {
  union { __hip_bfloat16 h; short s; } u;
  u.h = __float2bfloat16(f);   // hardware cvt (RNE), pairs fuse to v_cvt_pk_bf16_f32
  return u.s;
}

__device__ __forceinline__ void gload_lds16(const void* g, void* l) {
  __builtin_amdgcn_global_load_lds(
      (const __attribute__((address_space(1))) unsigned int*)g,
      (__attribute__((address_space(3))) unsigned int*)l, 16, 0, 0);
}

// key index -> position within vti's interleaved row (16B slot holds keys
// {32c+4g..+3, 32c+16+4g..+3} so PV A-frags are single b128 reads)
__device__ __forceinline__ int vperm(int k) {
  return (k & ~31) | (k & 3) | (((k >> 4) & 1) << 2) | (((k >> 2) & 3) << 3);
}

// ---------------------------------------------------------------------------
// fp32 -> bf16 cast, all three tensors in one launch (G13 vectorized)
// ---------------------------------------------------------------------------
__global__ void cvt_bf16_3(const float* __restrict__ s0, unsigned short* __restrict__ d0, int n0,
                           const float* __restrict__ s1, unsigned short* __restrict__ d1, int n1,
                           const float* __restrict__ s2, unsigned short* __restrict__ d2, int n2) {
  int i = (blockIdx.x * blockDim.x + threadIdx.x) * 8;
  const int stride = gridDim.x * blockDim.x * 8;
  const int t01 = n0 + n1, tot = n0 + n1 + n2;
  for (; i < tot; i += stride) {
    const float* s; unsigned short* d; int off;
    if (i < n0)      { s = s0; d = d0; off = i; }
    else if (i < t01){ s = s1; d = d1; off = i - n0; }
    else             { s = s2; d = d2; off = i - t01; }
    float4 a = *(const float4*)(s + off);
    float4 b = *(const float4*)(s + off + 4);
    union { unsigned short u[8]; int4 v; } r;
    r.u[0] = (unsigned short)f2bfs(a.x); r.u[1] = (unsigned short)f2bfs(a.y);
    r.u[2] = (unsigned short)f2bfs(a.z); r.u[3] = (unsigned short)f2bfs(a.w);
    r.u[4] = (unsigned short)f2bfs(b.x); r.u[5] = (unsigned short)f2bfs(b.y);
    r.u[6] = (unsigned short)f2bfs(b.z); r.u[7] = (unsigned short)f2bfs(b.w);
    *(int4*)(d + off) = r.v;
  }
}

// ---------------------------------------------------------------------------
// Epilogues
// ---------------------------------------------------------------------------
struct EpiQKV {
  const float* bias;
  unsigned short* qs; unsigned short* ks; unsigned short* vti;
  __device__ void operator()(int row, int col, float v) const {
    float val = v + bias[col];
    const int which = col >> 11;          // 0:q 1:k 2:v  (block-uniform)
    const int h = (col >> 7) & 15;
    const int d = col & 127;
    const int b = row >> 11, l = row & (SEQ - 1);
    if (which == 0) {
      qs[(((unsigned)(b * NHEAD + h) * SEQ) + l) * HDIM + d] = (unsigned short)f2bfs(val * QSCALE);
    } else if (which == 1) {
      ks[(((unsigned)(b * NHEAD + h) * SEQ) + l) * HDIM + d] = (unsigned short)f2bfs(val);
    } else {
      // V stored pre-transposed + key-interleaved: [B,H,D,SEQperm]
      vti[(((unsigned)(b * NHEAD + h) * HDIM) + d) * SEQ + vperm(l)] = (unsigned short)f2bfs(val);
    }
  }
};

struct EpiOut {
  const float* bias;
  float* out;
  __device__ void operator()(int row, int col, float v) const {
    out[(size_t)row * EMBD + col] = v + bias[col];
  }
};

// ---------------------------------------------------------------------------
// gemm1 (QKV): 256x256 tile, BK=64, 8 waves, 8-phase staggered schedule
// (round-10 measured-best: 150.2 us, FETCH 94 MB, conflicts 0).
// ---------------------------------------------------------------------------
__global__ __launch_bounds__(512, 2) void gemm_qkv8(
    const unsigned short* __restrict__ A, const unsigned short* __restrict__ B,
    EpiQKV epi) {
  __shared__ __align__(16) unsigned short lds[2][32768];
  const int tid = threadIdx.x, w = tid >> 6, lane = tid & 63;
  const int g = lane >> 4, lr = lane & 15;
  const int wm = w >> 2, wn = w & 3;
  const int m0 = ((int)blockIdx.x / 24) * 256;
  const int n0 = ((int)blockIdx.x % 24) * 256;
  constexpr int K = 2048;
  constexpr int nt = K / 64;   // 32

  const int srow = tid >> 3, sslot = tid & 7;

  auto stageH = [&](int t, int sel, int hh) {
    const unsigned short* src = sel ? B : A;
    const int base0 = sel ? n0 : m0;
    const int kel = t * 64 + ((sslot ^ (srow & 7)) << 3);
#pragma unroll
    for (int l = 0; l < 2; ++l)
      gload_lds16(src + (size_t)(base0 + hh * 128 + l * 64 + srow) * K + kel,
                  &lds[t & 1][sel * 16384 + hh * 8192 + (l * 512 + tid) * 8]);
  };
  auto rdA = [&](int buf, int Mh, int kk, int fr) -> bf16x8 {
    const int r = Mh * 128 + wm * 64 + fr * 16 + lr;
    return *(const bf16x8*)&lds[buf][r * 64 + (((kk * 4 + g) ^ (r & 7)) << 3)];
  };
  auto rdB = [&](int buf, int Nh, int kk, int fb) -> bf16x8 {
    const int r = Nh * 128 + wn * 32 + fb * 16 + lr;
    return *(const bf16x8*)&lds[buf][16384 + r * 64 + (((kk * 4 + g) ^ (r & 7)) << 3)];
  };

  f32x4 acc[8][4] = {};            // [Mh*4+fr][Nh*2+fb]
  bf16x8 a[4][2], bl[2][2], bh[2][2];

  // prologue: tile 0 fully + tile 1 {A-lo, B-lo, B-hi}
  stageH(0, 0, 0); stageH(0, 0, 1); stageH(0, 1, 0); stageH(0, 1, 1);
  stageH(1, 0, 0); stageH(1, 1, 0); stageH(1, 1, 1);
  asm volatile("s_waitcnt vmcnt(6)" ::: "memory");   // tile 0 landed
  __builtin_amdgcn_s_barrier();

  for (int t = 0; t < nt; ++t) {
    const int buf = t & 1;
    // ---- phase 1: (M0,N0); read A-lo + B-lo; stage t+1.A-hi (other buf)
#pragma unroll
    for (int fr = 0; fr < 4; ++fr) { a[fr][0] = rdA(buf, 0, 0, fr); a[fr][1] = rdA(buf, 0, 1, fr); }
#pragma unroll
    for (int fb = 0; fb < 2; ++fb) { bl[fb][0] = rdB(buf, 0, 0, fb); bl[fb][1] = rdB(buf, 0, 1, fb); }
    if (t + 1 < nt) stageH(t + 1, 0, 1);
    __builtin_amdgcn_s_barrier();
    asm volatile("s_waitcnt lgkmcnt(0)" ::: "memory");
    __builtin_amdgcn_s_setprio(1);
#pragma unroll
    for (int fr = 0; fr < 4; ++fr)
#pragma unroll
      for (int fb = 0; fb < 2; ++fb)
#pragma unroll
        for (int kk = 0; kk < 2; ++kk)
          acc[fr][fb] = __builtin_amdgcn_mfma_f32_16x16x32_bf16(a[fr][kk], bl[fb][kk], acc[fr][fb], 0, 0, 0);
    __builtin_amdgcn_s_setprio(0);
    __builtin_amdgcn_s_barrier();
    // ---- phase 2: (M0,N1); read B-hi; stage t+2.A-lo (current buf, dead)
#pragma unroll
    for (int fb = 0; fb < 2; ++fb) { bh[fb][0] = rdB(buf, 1, 0, fb); bh[fb][1] = rdB(buf, 1, 1, fb); }
    if (t + 2 < nt) stageH(t + 2, 0, 0);
    __builtin_amdgcn_s_barrier();
    asm volatile("s_waitcnt lgkmcnt(0)" ::: "memory");
    __builtin_amdgcn_s_setprio(1);
#pragma unroll
    for (int fr = 0; fr < 4; ++fr)
#pragma unroll
      for (int fb = 0; fb < 2; ++fb)
#pragma unroll
        for (int kk = 0; kk < 2; ++kk)
          acc[fr][2 + fb] = __builtin_amdgcn_mfma_f32_16x16x32_bf16(a[fr][kk], bh[fb][kk], acc[fr][2 + fb], 0, 0, 0);
    __builtin_amdgcn_s_setprio(0);
    __builtin_amdgcn_s_barrier();
    // ---- phase 3: (M1,N1); read A-hi; stage t+2.B-lo (dead since p1)
#pragma unroll
    for (int fr = 0; fr < 4; ++fr) { a[fr][0] = rdA(buf, 1, 0, fr); a[fr][1] = rdA(buf, 1, 1, fr); }
    if (t + 2 < nt) stageH(t + 2, 1, 0);
    __builtin_amdgcn_s_barrier();
    asm volatile("s_waitcnt lgkmcnt(0)" ::: "memory");
    __builtin_amdgcn_s_setprio(1);
#pragma unroll
    for (int fr = 0; fr < 4; ++fr)
#pragma unroll
      for (int fb = 0; fb < 2; ++fb)
#pragma unroll
        for (int kk = 0; kk < 2; ++kk)
          acc[4 + fr][2 + fb] = __builtin_amdgcn_mfma_f32_16x16x32_bf16(a[fr][kk], bh[fb][kk], acc[4 + fr][2 + fb], 0, 0, 0);
    __builtin_amdgcn_s_setprio(0);
    __builtin_amdgcn_s_barrier();
    // ---- phase 4: (M1,N0); no reads (A-hi + B-lo in regs); stage t+2.B-hi
    if (t + 2 < nt) stageH(t + 2, 1, 1);
    __builtin_amdgcn_s_barrier();
    __builtin_amdgcn_s_setprio(1);
#pragma unroll
    for (int fr = 0; fr < 4; ++fr)
#pragma unroll
      for (int fb = 0; fb < 2; ++fb)
#pragma unroll
        for (int kk = 0; kk < 2; ++kk)
          acc[4 + fr][fb] = __builtin_amdgcn_mfma_f32_16x16x32_bf16(a[fr][kk], bl[fb][kk], acc[4 + fr][fb], 0, 0, 0);
    __builtin_amdgcn_s_setprio(0);
    // ---- K-tile boundary: counted vmcnt proves tile t+1 fully landed
    if (t + 2 < nt) {
      asm volatile("s_waitcnt vmcnt(6)" ::: "memory");
    } else if (t + 1 < nt) {
      asm volatile("s_waitcnt vmcnt(0)" ::: "memory");
    }
    __builtin_amdgcn_s_barrier();
  }

  // epilogue: interleaved-quadrant positions
#pragma unroll
  for (int mf = 0; mf < 8; ++mf)
#pragma unroll
    for (int nf = 0; nf < 4; ++nf) {
      const int row = m0 + (mf >> 2) * 128 + wm * 64 + (mf & 3) * 16 + g * 4;
      const int col = n0 + (nf >> 1) * 128 + wn * 32 + (nf & 1) * 16 + lr;
#pragma unroll
      for (int jr = 0; jr < 4; ++jr) epi(row + jr, col, acc[mf][nf][jr]);
    }
}

// ---------------------------------------------------------------------------
// GEMM body (m97 structure, 128x128 tile, BK=32) — kept for the output GEMM
// ---------------------------------------------------------------------------
template <class Epi>
__device__ void gemm_body(unsigned short* ldsbuf,
                          const unsigned short* __restrict__ A,
                          const unsigned short* __restrict__ B,
                          int K, int m0, int n0, Epi epi) {
  const int tid = threadIdx.x;
  const int w = tid >> 6, lane = tid & 63;
  const int g = lane >> 4, lr = lane & 15;
  const int wm = w >> 1, wn = w & 1;
  const int srow = lane >> 2, sslot = lane & 3;

  f32x4 acc[4][4] = {};

  auto stage = [&](int buf, int t) {
    const int k0 = t * 32;
    unsigned short* slot = ldsbuf + buf * 8192;
#pragma unroll
    for (int c2 = 0; c2 < 2; ++c2) {
      const int chunk = 2 * w + c2;
      const int row = chunk * 16 + srow;
      const int kel = k0 + ((sslot ^ ((row >> 1) & 3)) << 3);
      gload_lds16(A + (size_t)(m0 + row) * K + kel, &slot[chunk * 512]);
      gload_lds16(B + (size_t)(n0 + row) * K + kel, &slot[4096 + chunk * 512]);
    }
  };

  const int nt = K >> 5;
  int cur = 0;
  stage(0, 0);
  asm volatile("s_waitcnt vmcnt(0)" ::: "memory");
  __syncthreads();

  for (int t = 0; t < nt; ++t) {
    if (t + 1 < nt) stage(cur ^ 1, t + 1);
    const unsigned short* slot = ldsbuf + cur * 8192;
    bf16x8 af[4], bq[4];
#pragma unroll
    for (int fr = 0; fr < 4; ++fr) {
      const int r = wm * 64 + fr * 16 + lr;
      af[fr] = *(const bf16x8*)&slot[r * 32 + ((g ^ ((r >> 1) & 3)) << 3)];
      const int rn = wn * 64 + fr * 16 + lr;
      bq[fr] = *(const bf16x8*)&slot[4096 + rn * 32 + ((g ^ ((rn >> 1) & 3)) << 3)];
    }
#pragma unroll
    for (int i = 0; i < 4; ++i)
#pragma unroll
      for (int j = 0; j < 4; ++j)
        acc[i][j] = __builtin_amdgcn_mfma_f32_16x16x32_bf16(af[i], bq[j], acc[i][j], 0, 0, 0);
    asm volatile("s_waitcnt vmcnt(0)" ::: "memory");
    __syncthreads();
    cur ^= 1;
  }

#pragma unroll
  for (int i = 0; i < 4; ++i)
#pragma unroll
    for (int j = 0; j < 4; ++j) {
      const int row = m0 + wm * 64 + i * 16 + g * 4;
      const int col = n0 + wn * 64 + j * 16 + lr;
#pragma unroll
      for (int jr = 0; jr < 4; ++jr) epi(row + jr, col, acc[i][j][jr]);
    }
}

// ---------------------------------------------------------------------------
// attn_avg body: grouped-GEMM over heads with ring-3 LDS + counted vmcnt.
// ---------------------------------------------------------------------------
__device__ void attn_avg_body(unsigned short* lds,
                              const unsigned short* __restrict__ qs,
                              const unsigned short* __restrict__ ks,
                              const float* __restrict__ c_s,
                              float* __restrict__ out, int blk) {
  const int tid = threadIdx.x, w = tid >> 6, lane = tid & 63;
  const int g = lane >> 4, lr = lane & 15;
  const int wm = w >> 1, wn = w & 1;
  const int k0 = (blk & 15) * 128, q0 = ((blk >> 4) & 15) * 128, b = blk >> 8;
  const int srow = lane >> 2, sslot = lane & 3;

  constexpr int NC = NHEAD * 4;   // 64 chunks

  auto stage = [&](int c) {
    const size_t bh = ((size_t)(b * NHEAD + (c >> 2))) * SEQ * HDIM + (c & 3) * 32;
    unsigned short* slot = lds + (c % 3) * 8192;
#pragma unroll
    for (int c2 = 0; c2 < 2; ++c2) {
      const int chunk = 2 * w + c2;            // 0..7, 16 rows each
      const int row = chunk * 16 + srow;
      const int kel = (sslot ^ ((row >> 1) & 3)) << 3;
      gload_lds16(qs + bh + (size_t)(q0 + row) * HDIM + kel, &slot[chunk * 512]);
      gload_lds16(ks + bh + (size_t)(k0 + row) * HDIM + kel, &slot[4096 + chunk * 512]);
    }
  };

  f32x4 acc[4][4] = {};

  stage(0); stage(1);
  asm volatile("s_waitcnt vmcnt(4)" ::: "memory");
  asm volatile("s_barrier" ::: "memory");

  for (int hc = 0; hc < NHEAD; ++hc) {
    f32x4 st[4][4] = {};
#pragma unroll
    for (int dq = 0; dq < 4; ++dq) {
      const int c = hc * 4 + dq;
      if (c + 2 < NC) stage(c + 2);
      const unsigned short* slot = lds + (c % 3) * 8192;
      bf16x8 af[4], bq[4];
#pragma unroll
      for (int fr = 0; fr < 4; ++fr) {
        const int rq = wm * 64 + fr * 16 + lr;
        af[fr] = *(const bf16x8*)&slot[rq * 32 + ((g ^ ((rq >> 1) & 3)) << 3)];
        const int rk = wn * 64 + fr * 16 + lr;
        bq[fr] = *(const bf16x8*)&slot[4096 + rk * 32 + ((g ^ ((rk >> 1) & 3)) << 3)];
      }
#pragma unroll
      for (int i = 0; i < 4; ++i)
#pragma unroll
        for (int j = 0; j < 4; ++j)
          st[i][j] = __builtin_amdgcn_mfma_f32_16x16x32_bf16(af[i], bq[j], st[i][j], 0, 0, 0);
      if (c + 2 < NC) {
        asm volatile("s_waitcnt vmcnt(4)" ::: "memory");
        asm volatile("s_barrier" ::: "memory");
      } else if (c + 1 < NC) {
        asm volatile("s_waitcnt vmcnt(0)" ::: "memory");
        asm volatile("s_barrier" ::: "memory");
      }
    }
    const int chq = (b * NHEAD + hc) * SEQ + q0 + wm * 64 + g * 4;
#pragma unroll
    for (int i = 0; i < 4; ++i) {
      const f32x4 cq = *(const f32x4*)&c_s[chq + i * 16];
#pragma unroll
      for (int j = 0; j < 4; ++j)
#pragma unroll
        for (int jr = 0; jr < 4; ++jr)
          acc[i][j][jr] += __builtin_exp2f(st[i][j][jr] - cq[jr]);
    }
  }

#pragma unroll
  for (int i = 0; i < 4; ++i)
#pragma unroll
    for (int jr = 0; jr < 4; ++jr) {
      const size_t rowoff = (size_t)(b * SEQ + q0 + wm * 64 + i * 16 + g * 4 + jr) * SEQ;
#pragma unroll
      for (int j = 0; j < 4; ++j)
        out[rowoff + k0 + wn * 64 + j * 16 + lr] = acc[i][j][jr];
    }
}

// ---------------------------------------------------------------------------
// Fused tail, LPT range-split: blocks 0..511 = attn_avg (LONGER blocks first),
// 512..1023 = output-GEMM tiles (shorter; fill the ramp-down).
// ---------------------------------------------------------------------------
__global__ __launch_bounds__(256, 2) void tail_fused(
    const unsigned short* __restrict__ ctx, const unsigned short* __restrict__ wo,
    const float* __restrict__ b_out, float* __restrict__ out,
    const unsigned short* __restrict__ qs, const unsigned short* __restrict__ ks,
    const float* __restrict__ c_s, float* __restrict__ attn_avg) {
  __shared__ __align__(16) unsigned short lds[3 * 8192];
  const int id = blockIdx.x;
  if (id < 512) {
    attn_avg_body(lds, qs, ks, c_s, attn_avg, id);
  } else {
    const int sub = id - 512;
    gemm_body(lds, ctx, wo, EMBD, (sub >> 4) * 128, (sub & 15) * 128, EpiOut{b_out, out});
  }
}

// ---------------------------------------------------------------------------
// Flash attention fwd v3 (round-8 proven). Grid: B*H*(SEQ/128) = 512 x 512thr.
// ---------------------------------------------------------------------------
__global__ __launch_bounds__(512, 4) void flash_fwd(
    const unsigned short* __restrict__ qs, const unsigned short* __restrict__ ks,
    const unsigned short* __restrict__ vti, unsigned short* __restrict__ ctx,
    float* __restrict__ c_s) {
  __shared__ __align__(16) unsigned short smem[32768];  // 2 bufs x (K 16KB + V^T 16KB)
  const int tid = threadIdx.x, w = tid >> 6, lane = tid & 63;
  const int g = lane >> 4, lr = lane & 15;
  const int blk = ((int)blockIdx.x & 7) * ((int)gridDim.x >> 3) + ((int)blockIdx.x >> 3);
  const int qt = blk & 15, h = (blk >> 4) & 15, b = blk >> 8;
  const int q0 = qt * 128;
  const size_t bh = ((size_t)(b * NHEAD + h)) * SEQ * HDIM;

  const int qrow = q0 + w * 16 + lr;
  bf16x8 qf[4];
#pragma unroll
  for (int kk = 0; kk < 4; ++kk)
    qf[kk] = *(const bf16x8*)(qs + bh + (size_t)qrow * HDIM + kk * 32 + g * 8);

  float m_run = -1e30f, l_run = 0.f;
  f32x4 o[8] = {};

  auto stage = [&](int buf, int t) {
    unsigned short* kt = smem + buf * 16384;
    unsigned short* vt = kt + 8192;
    const int key0 = t * 64;
#pragma unroll
    for (int c = 0; c < 2; ++c) {
      const int chunk = w * 2 + c;
      const int key = chunk * 4 + (lane >> 4);
      const int slot = lane & 15;
      gload_lds16(ks + bh + (size_t)(key0 + key) * HDIM + ((slot ^ (key & 7)) * 8),
                  &kt[chunk * 512]);
    }
#pragma unroll
    for (int c = 0; c < 2; ++c) {
      const int chunk = w * 2 + c;
      const int d = chunk * 8 + (lane >> 3);
      const int slot = lane & 7;
      gload_lds16(vti + bh + (size_t)d * SEQ + key0 + ((slot ^ (d & 7)) * 8),
                  &vt[chunk * 512]);
    }
  };

  stage(0, 0);
  asm volatile("s_waitcnt vmcnt(0)" ::: "memory");
  __syncthreads();
  int cur = 0;

  for (int t = 0; t < 32; ++t) {
    if (t + 1 < 32) stage(cur ^ 1, t + 1);
    const unsigned short* kt = smem + cur * 16384;
    const unsigned short* vt = kt + 8192;

    f32x4 st[4] = {};
    __builtin_amdgcn_s_setprio(1);
#pragma unroll
    for (int kk = 0; kk < 4; ++kk)
#pragma unroll
      for (int fc = 0; fc < 4; ++fc) {
        const int key = fc * 16 + lr;
        bf16x8 kf = *(const bf16x8*)&kt[key * 128 + (((kk * 4 + g) ^ (key & 7)) << 3)];
        st[fc] = __builtin_amdgcn_mfma_f32_16x16x32_bf16(kf, qf[kk], st[fc], 0, 0, 0);
      }
    __builtin_amdgcn_s_setprio(0);

    float tmax = st[0][0];
#pragma unroll
    for (int fc = 0; fc < 4; ++fc)
#pragma unroll
      for (int j = 0; j < 4; ++j) tmax = fmaxf(tmax, st[fc][j]);
    tmax = fmaxf(tmax, __shfl_xor(tmax, 16));
    tmax = fmaxf(tmax, __shfl_xor(tmax, 32));
    if (!__all(tmax <= m_run + 8.f)) {
      const float m_new = fmaxf(m_run, tmax);
      const float corr = __builtin_exp2f(m_run - m_new);
      l_run *= corr;
#pragma unroll
      for (int fd = 0; fd < 8; ++fd)
#pragma unroll
        for (int j = 0; j < 4; ++j) o[fd][j] *= corr;
      m_run = m_new;
    }
    float pt[4][4];
    float tsum = 0.f;
#pragma unroll
    for (int fc = 0; fc < 4; ++fc)
#pragma unroll
      for (int j = 0; j < 4; ++j) {
        const float e = __builtin_exp2f(st[fc][j] - m_run);
        pt[fc][j] = e; tsum += e;
      }
    tsum += __shfl_xor(tsum, 16);
    tsum += __shfl_xor(tsum, 32);
    l_run += tsum;

    bf16x8 pb[2];
#pragma unroll
    for (int c = 0; c < 2; ++c)
#pragma unroll
      for (int j = 0; j < 4; ++j) {
        pb[c][j]     = f2bfs(pt[2 * c][j]);
        pb[c][4 + j] = f2bfs(pt[2 * c + 1][j]);
      }

    __builtin_amdgcn_s_setprio(1);
#pragma unroll
    for (int fd = 0; fd < 8; ++fd) {
      const int d = fd * 16 + lr;
#pragma unroll
      for (int c = 0; c < 2; ++c) {
        bf16x8 vf = *(const bf16x8*)&vt[d * 64 + (((c * 4 + g) ^ (d & 7)) << 3)];
        o[fd] = __builtin_amdgcn_mfma_f32_16x16x32_bf16(vf, pb[c], o[fd], 0, 0, 0);
      }
    }
    __builtin_amdgcn_s_setprio(0);

    asm volatile("s_waitcnt vmcnt(0)" ::: "memory");
    __syncthreads();
    cur ^= 1;
  }

  const float inv_l = 1.0f / l_run;
  unsigned short* trp = smem + w * 2176;
#pragma unroll
  for (int fd = 0; fd < 8; ++fd)
#pragma unroll
    for (int jp = 0; jp < 2; ++jp) {
      const int d = fd * 16 + 4 * g + 2 * jp;
      unsigned valu = (unsigned)(unsigned short)f2bfs(o[fd][2 * jp] * inv_l) |
                      ((unsigned)(unsigned short)f2bfs(o[fd][2 * jp + 1] * inv_l) << 16);
      *(unsigned*)((char*)trp + lr * 272 + d * 2) = valu;
    }
  __syncthreads();
#pragma unroll
  for (int r4 = 0; r4 < 4; ++r4) {
    const int row = r4 * 4 + g;
    bf16x8 valv = *(const bf16x8*)((char*)trp + row * 272 + lr * 16);
    *(bf16x8*)(ctx + (size_t)(b * SEQ + q0 + w * 16 + row) * EMBD + h * HDIM + lr * 8) = valv;
  }
  if (g == 0) {
    const int ridx = (b * NHEAD + h) * SEQ + q0 + w * 16 + lr;
    c_s[ridx] = m_run + __log2f(l_run) + 4.0f;
  }
}

// ---------------------------------------------------------------------------
extern "C" void kernel_launch(void* const* d_in, const int* in_sizes, int n_in,
                              void* d_out, int out_size, void* d_ws, size_t ws_size,
                              hipStream_t stream) {
  const float* query = (const float*)d_in[0];
  // d_in[1] (key), d_in[2] (value) are ignored by the reference module
  const float* W_in  = (const float*)d_in[3];
  const float* b_in  = (const float*)d_in[4];
  const float* W_out = (const float*)d_in[5];
  const float* b_out = (const float*)d_in[6];

  float* out      = (float*)d_out;                       // [B,L,E]
  float* attn_avg = out + (size_t)BATCH * SEQ * EMBD;    // [B,L,L]

  char* ws = (char*)d_ws;
  auto take = [&](size_t bytes) { char* p = ws; ws += bytes; return p; };
  const size_t szBLE = (size_t)BATCH * SEQ * EMBD * 2;   // bf16 [B*L, E]
  unsigned short* qbf = (unsigned short*)take(szBLE);
  unsigned short* wi  = (unsigned short*)take((size_t)3 * EMBD * EMBD * 2);
  unsigned short* wo  = (unsigned short*)take((size_t)EMBD * EMBD * 2);
  unsigned short* qsb = (unsigned short*)take(szBLE);    // [B,H,L,D] *QSCALE
  unsigned short* ksb = (unsigned short*)take(szBLE);    // [B,H,L,D]
  unsigned short* vti = (unsigned short*)take(szBLE);    // [B,H,D,Lperm]
  unsigned short* ctx = (unsigned short*)take(szBLE);    // [B,L,H,D] == [B*L, E]
  float* c_s = (float*)take((size_t)BATCH * NHEAD * SEQ * 4);

  cvt_bf16_3<<<2048, 256, 0, stream>>>(query, qbf, BATCH * SEQ * EMBD,
                                       W_in, wi, 3 * EMBD * EMBD,
                                       W_out, wo, EMBD * EMBD);

  // qkv = query @ W_in^T + b_in  (M=4096, N=6144, K=2048), 8-phase 256^2
  gemm_qkv8<<<16 * 24, 512, 0, stream>>>(qbf, wi, EpiQKV{b_in, qsb, ksb, vti});
  // attention (writes ctx, c_s)
  flash_fwd<<<BATCH * NHEAD * (SEQ / 128), 512, 0, stream>>>(qsb, ksb, vti, ctx, c_s);
  // fused tail, LPT: attn_avg first (blocks 0-511), output GEMM (512-1023)
  tail_fused<<<1024, 256, 0, stream>>>(ctx, wo, b_out, out, qsb, ksb, c_s, attn_avg);
}

// Round 14
// 367.285 us; speedup vs baseline: 1.0388x; 1.0053x over previous
//
#include <hip/hip_runtime.h>
#include <hip/hip_bf16.h>
#include <stdint.h>
#include <stddef.h>

// Problem constants (fixed by the reference)
constexpr int BATCH = 2;
constexpr int SEQ   = 2048;
constexpr int EMBD  = 2048;
constexpr int NHEAD = 16;
constexpr int HDIM  = 128;
// 1/sqrt(128) * log2(e): scores land in log2-domain -> exp2 directly
constexpr float QSCALE = 0.08838834764831845f * 1.4426950408889634f;

typedef short bf16x8 __attribute__((ext_vector_type(8)));
typedef float f32x4  __attribute__((ext_vector_type(4)));

__device__ __forceinline__ short f2bfs(float f) {
  union { __hip_bfloat16 h; short s; } u;
  u.h = __float2bfloat16(f);   // hardware cvt (RNE), pairs fuse to v_cvt_pk_bf16_f32
  return u.s;
}

__device__ __forceinline__ void gload_lds16(const void* g, void* l) {
  __builtin_amdgcn_global_load_lds(
      (const __attribute__((address_space(1))) unsigned int*)g,
      (__attribute__((address_space(3))) unsigned int*)l, 16, 0, 0);
}

// key index -> position within vti's interleaved row (16B slot holds keys
// {32c+4g..+3, 32c+16+4g..+3} so PV A-frags are single b128 reads)
__device__ __forceinline__ int vperm(int k) {
  return (k & ~31) | (k & 3) | (((k >> 4) & 1) << 2) | (((k >> 2) & 3) << 3);
}

// ---------------------------------------------------------------------------
// fp32 -> bf16 cast, all three tensors in one launch (G13 vectorized)
// ---------------------------------------------------------------------------
__global__ void cvt_bf16_3(const float* __restrict__ s0, unsigned short* __restrict__ d0, int n0,
                           const float* __restrict__ s1, unsigned short* __restrict__ d1, int n1,
                           const float* __restrict__ s2, unsigned short* __restrict__ d2, int n2) {
  int i = (blockIdx.x * blockDim.x + threadIdx.x) * 8;
  const int stride = gridDim.x * blockDim.x * 8;
  const int t01 = n0 + n1, tot = n0 + n1 + n2;
  for (; i < tot; i += stride) {
    const float* s; unsigned short* d; int off;
    if (i < n0)      { s = s0; d = d0; off = i; }
    else if (i < t01){ s = s1; d = d1; off = i - n0; }
    else             { s = s2; d = d2; off = i - t01; }
    float4 a = *(const float4*)(s + off);
    float4 b = *(const float4*)(s + off + 4);
    union { unsigned short u[8]; int4 v; } r;
    r.u[0] = (unsigned short)f2bfs(a.x); r.u[1] = (unsigned short)f2bfs(a.y);
    r.u[2] = (unsigned short)f2bfs(a.z); r.u[3] = (unsigned short)f2bfs(a.w);
    r.u[4] = (unsigned short)f2bfs(b.x); r.u[5] = (unsigned short)f2bfs(b.y);
    r.u[6] = (unsigned short)f2bfs(b.z); r.u[7] = (unsigned short)f2bfs(b.w);
    *(int4*)(d + off) = r.v;
  }
}

// ---------------------------------------------------------------------------
// Epilogues
// ---------------------------------------------------------------------------
struct EpiQKV {
  const float* bias;
  unsigned short* qs; unsigned short* ks; unsigned short* vti;
  __device__ void operator()(int row, int col, float v) const {
    float val = v + bias[col];
    const int which = col >> 11;          // 0:q 1:k 2:v  (block-uniform)
    const int h = (col >> 7) & 15;
    const int d = col & 127;
    const int b = row >> 11, l = row & (SEQ - 1);
    if (which == 0) {
      qs[(((unsigned)(b * NHEAD + h) * SEQ) + l) * HDIM + d] = (unsigned short)f2bfs(val * QSCALE);
    } else if (which == 1) {
      ks[(((unsigned)(b * NHEAD + h) * SEQ) + l) * HDIM + d] = (unsigned short)f2bfs(val);
    } else {
      // V stored pre-transposed + key-interleaved: [B,H,D,SEQperm]
      vti[(((unsigned)(b * NHEAD + h) * HDIM) + d) * SEQ + vperm(l)] = (unsigned short)f2bfs(val);
    }
  }
};

struct EpiOut {
  const float* bias;
  float* out;
  __device__ void operator()(int row, int col, float v) const {
    out[(size_t)row * EMBD + col] = v + bias[col];
  }
};

// ---------------------------------------------------------------------------
// gemm1 (QKV): 256x256 tile, BK=64, 8 waves, 8-phase staggered schedule
// (round-10 measured-best: 150.2 us, FETCH 94 MB, conflicts 0).
// ---------------------------------------------------------------------------
__global__ __launch_bounds__(512, 2) void gemm_qkv8(
    const unsigned short* __restrict__ A, const unsigned short* __restrict__ B,
    EpiQKV epi) {
  __shared__ __align__(16) unsigned short lds[2][32768];
  const int tid = threadIdx.x, w = tid >> 6, lane = tid & 63;
  const int g = lane >> 4, lr = lane & 15;
  const int wm = w >> 2, wn = w & 3;
  const int m0 = ((int)blockIdx.x / 24) * 256;
  const int n0 = ((int)blockIdx.x % 24) * 256;
  constexpr int K = 2048;
  constexpr int nt = K / 64;   // 32

  const int srow = tid >> 3, sslot = tid & 7;

  auto stageH = [&](int t, int sel, int hh) {
    const unsigned short* src = sel ? B : A;
    const int base0 = sel ? n0 : m0;
    const int kel = t * 64 + ((sslot ^ (srow & 7)) << 3);
#pragma unroll
    for (int l = 0; l < 2; ++l)
      gload_lds16(src + (size_t)(base0 + hh * 128 + l * 64 + srow) * K + kel,
                  &lds[t & 1][sel * 16384 + hh * 8192 + (l * 512 + tid) * 8]);
  };
  auto rdA = [&](int buf, int Mh, int kk, int fr) -> bf16x8 {
    const int r = Mh * 128 + wm * 64 + fr * 16 + lr;
    return *(const bf16x8*)&lds[buf][r * 64 + (((kk * 4 + g) ^ (r & 7)) << 3)];
  };
  auto rdB = [&](int buf, int Nh, int kk, int fb) -> bf16x8 {
    const int r = Nh * 128 + wn * 32 + fb * 16 + lr;
    return *(const bf16x8*)&lds[buf][16384 + r * 64 + (((kk * 4 + g) ^ (r & 7)) << 3)];
  };

  f32x4 acc[8][4] = {};            // [Mh*4+fr][Nh*2+fb]
  bf16x8 a[4][2], bl[2][2], bh[2][2];

  // prologue: tile 0 fully + tile 1 {A-lo, B-lo, B-hi}
  stageH(0, 0, 0); stageH(0, 0, 1); stageH(0, 1, 0); stageH(0, 1, 1);
  stageH(1, 0, 0); stageH(1, 1, 0); stageH(1, 1, 1);
  asm volatile("s_waitcnt vmcnt(6)" ::: "memory");   // tile 0 landed
  __builtin_amdgcn_s_barrier();

  for (int t = 0; t < nt; ++t) {
    const int buf = t & 1;
    // ---- phase 1: (M0,N0); read A-lo + B-lo; stage t+1.A-hi (other buf)
#pragma unroll
    for (int fr = 0; fr < 4; ++fr) { a[fr][0] = rdA(buf, 0, 0, fr); a[fr][1] = rdA(buf, 0, 1, fr); }
#pragma unroll
    for (int fb = 0; fb < 2; ++fb) { bl[fb][0] = rdB(buf, 0, 0, fb); bl[fb][1] = rdB(buf, 0, 1, fb); }
    if (t + 1 < nt) stageH(t + 1, 0, 1);
    __builtin_amdgcn_s_barrier();
    asm volatile("s_waitcnt lgkmcnt(0)" ::: "memory");
    __builtin_amdgcn_s_setprio(1);
#pragma unroll
    for (int fr = 0; fr < 4; ++fr)
#pragma unroll
      for (int fb = 0; fb < 2; ++fb)
#pragma unroll
        for (int kk = 0; kk < 2; ++kk)
          acc[fr][fb] = __builtin_amdgcn_mfma_f32_16x16x32_bf16(a[fr][kk], bl[fb][kk], acc[fr][fb], 0, 0, 0);
    __builtin_amdgcn_s_setprio(0);
    __builtin_amdgcn_s_barrier();
    // ---- phase 2: (M0,N1); read B-hi; stage t+2.A-lo (current buf, dead)
#pragma unroll
    for (int fb = 0; fb < 2; ++fb) { bh[fb][0] = rdB(buf, 1, 0, fb); bh[fb][1] = rdB(buf, 1, 1, fb); }
    if (t + 2 < nt) stageH(t + 2, 0, 0);
    __builtin_amdgcn_s_barrier();
    asm volatile("s_waitcnt lgkmcnt(0)" ::: "memory");
    __builtin_amdgcn_s_setprio(1);
#pragma unroll
    for (int fr = 0; fr < 4; ++fr)
#pragma unroll
      for (int fb = 0; fb < 2; ++fb)
#pragma unroll
        for (int kk = 0; kk < 2; ++kk)
          acc[fr][2 + fb] = __builtin_amdgcn_mfma_f32_16x16x32_bf16(a[fr][kk], bh[fb][kk], acc[fr][2 + fb], 0, 0, 0);
    __builtin_amdgcn_s_setprio(0);
    __builtin_amdgcn_s_barrier();
    // ---- phase 3: (M1,N1); read A-hi; stage t+2.B-lo (dead since p1)
#pragma unroll
    for (int fr = 0; fr < 4; ++fr) { a[fr][0] = rdA(buf, 1, 0, fr); a[fr][1] = rdA(buf, 1, 1, fr); }
    if (t + 2 < nt) stageH(t + 2, 1, 0);
    __builtin_amdgcn_s_barrier();
    asm volatile("s_waitcnt lgkmcnt(0)" ::: "memory");
    __builtin_amdgcn_s_setprio(1);
#pragma unroll
    for (int fr = 0; fr < 4; ++fr)
#pragma unroll
      for (int fb = 0; fb < 2; ++fb)
#pragma unroll
        for (int kk = 0; kk < 2; ++kk)
          acc[4 + fr][2 + fb] = __builtin_amdgcn_mfma_f32_16x16x32_bf16(a[fr][kk], bh[fb][kk], acc[4 + fr][2 + fb], 0, 0, 0);
    __builtin_amdgcn_s_setprio(0);
    __builtin_amdgcn_s_barrier();
    // ---- phase 4: (M1,N0); no reads (A-hi + B-lo in regs); stage t+2.B-hi
    if (t + 2 < nt) stageH(t + 2, 1, 1);
    __builtin_amdgcn_s_barrier();
    __builtin_amdgcn_s_setprio(1);
#pragma unroll
    for (int fr = 0; fr < 4; ++fr)
#pragma unroll
      for (int fb = 0; fb < 2; ++fb)
#pragma unroll
        for (int kk = 0; kk < 2; ++kk)
          acc[4 + fr][fb] = __builtin_amdgcn_mfma_f32_16x16x32_bf16(a[fr][kk], bl[fb][kk], acc[4 + fr][fb], 0, 0, 0);
    __builtin_amdgcn_s_setprio(0);
    // ---- K-tile boundary: counted vmcnt proves tile t+1 fully landed
    if (t + 2 < nt) {
      asm volatile("s_waitcnt vmcnt(6)" ::: "memory");
    } else if (t + 1 < nt) {
      asm volatile("s_waitcnt vmcnt(0)" ::: "memory");
    }
    __builtin_amdgcn_s_barrier();
  }

  // epilogue: interleaved-quadrant positions
#pragma unroll
  for (int mf = 0; mf < 8; ++mf)
#pragma unroll
    for (int nf = 0; nf < 4; ++nf) {
      const int row = m0 + (mf >> 2) * 128 + wm * 64 + (mf & 3) * 16 + g * 4;
      const int col = n0 + (nf >> 1) * 128 + wn * 32 + (nf & 1) * 16 + lr;
#pragma unroll
      for (int jr = 0; jr < 4; ++jr) epi(row + jr, col, acc[mf][nf][jr]);
    }
}

// ---------------------------------------------------------------------------
// GEMM body (m97 structure, 128x128 tile, BK=32) — kept for the output GEMM
// ---------------------------------------------------------------------------
template <class Epi>
__device__ void gemm_body(unsigned short* ldsbuf,
                          const unsigned short* __restrict__ A,
                          const unsigned short* __restrict__ B,
                          int K, int m0, int n0, Epi epi) {
  const int tid = threadIdx.x;
  const int w = tid >> 6, lane = tid & 63;
  const int g = lane >> 4, lr = lane & 15;
  const int wm = w >> 1, wn = w & 1;
  const int srow = lane >> 2, sslot = lane & 3;

  f32x4 acc[4][4] = {};

  auto stage = [&](int buf, int t) {
    const int k0 = t * 32;
    unsigned short* slot = ldsbuf + buf * 8192;
#pragma unroll
    for (int c2 = 0; c2 < 2; ++c2) {
      const int chunk = 2 * w + c2;
      const int row = chunk * 16 + srow;
      const int kel = k0 + ((sslot ^ ((row >> 1) & 3)) << 3);
      gload_lds16(A + (size_t)(m0 + row) * K + kel, &slot[chunk * 512]);
      gload_lds16(B + (size_t)(n0 + row) * K + kel, &slot[4096 + chunk * 512]);
    }
  };

  const int nt = K >> 5;
  int cur = 0;
  stage(0, 0);
  asm volatile("s_waitcnt vmcnt(0)" ::: "memory");
  __syncthreads();

  for (int t = 0; t < nt; ++t) {
    if (t + 1 < nt) stage(cur ^ 1, t + 1);
    const unsigned short* slot = ldsbuf + cur * 8192;
    bf16x8 af[4], bq[4];
#pragma unroll
    for (int fr = 0; fr < 4; ++fr) {
      const int r = wm * 64 + fr * 16 + lr;
      af[fr] = *(const bf16x8*)&slot[r * 32 + ((g ^ ((r >> 1) & 3)) << 3)];
      const int rn = wn * 64 + fr * 16 + lr;
      bq[fr] = *(const bf16x8*)&slot[4096 + rn * 32 + ((g ^ ((rn >> 1) & 3)) << 3)];
    }
#pragma unroll
    for (int i = 0; i < 4; ++i)
#pragma unroll
      for (int j = 0; j < 4; ++j)
        acc[i][j] = __builtin_amdgcn_mfma_f32_16x16x32_bf16(af[i], bq[j], acc[i][j], 0, 0, 0);
    asm volatile("s_waitcnt vmcnt(0)" ::: "memory");
    __syncthreads();
    cur ^= 1;
  }

#pragma unroll
  for (int i = 0; i < 4; ++i)
#pragma unroll
    for (int j = 0; j < 4; ++j) {
      const int row = m0 + wm * 64 + i * 16 + g * 4;
      const int col = n0 + wn * 64 + j * 16 + lr;
#pragma unroll
      for (int jr = 0; jr < 4; ++jr) epi(row + jr, col, acc[i][j][jr]);
    }
}

// ---------------------------------------------------------------------------
// attn_avg body: grouped-GEMM over heads with ring-3 LDS + counted vmcnt.
// ---------------------------------------------------------------------------
__device__ void attn_avg_body(unsigned short* lds,
                              const unsigned short* __restrict__ qs,
                              const unsigned short* __restrict__ ks,
                              const float* __restrict__ c_s,
                              float* __restrict__ out, int blk) {
  const int tid = threadIdx.x, w = tid >> 6, lane = tid & 63;
  const int g = lane >> 4, lr = lane & 15;
  const int wm = w >> 1, wn = w & 1;
  const int k0 = (blk & 15) * 128, q0 = ((blk >> 4) & 15) * 128, b = blk >> 8;
  const int srow = lane >> 2, sslot = lane & 3;

  constexpr int NC = NHEAD * 4;   // 64 chunks

  auto stage = [&](int c) {
    const size_t bh = ((size_t)(b * NHEAD + (c >> 2))) * SEQ * HDIM + (c & 3) * 32;
    unsigned short* slot = lds + (c % 3) * 8192;
#pragma unroll
    for (int c2 = 0; c2 < 2; ++c2) {
      const int chunk = 2 * w + c2;            // 0..7, 16 rows each
      const int row = chunk * 16 + srow;
      const int kel = (sslot ^ ((row >> 1) & 3)) << 3;
      gload_lds16(qs + bh + (size_t)(q0 + row) * HDIM + kel, &slot[chunk * 512]);
      gload_lds16(ks + bh + (size_t)(k0 + row) * HDIM + kel, &slot[4096 + chunk * 512]);
    }
  };

  f32x4 acc[4][4] = {};

  stage(0); stage(1);
  asm volatile("s_waitcnt vmcnt(4)" ::: "memory");
  asm volatile("s_barrier" ::: "memory");

  for (int hc = 0; hc < NHEAD; ++hc) {
    f32x4 st[4][4] = {};
#pragma unroll
    for (int dq = 0; dq < 4; ++dq) {
      const int c = hc * 4 + dq;
      if (c + 2 < NC) stage(c + 2);
      const unsigned short* slot = lds + (c % 3) * 8192;
      bf16x8 af[4], bq[4];
#pragma unroll
      for (int fr = 0; fr < 4; ++fr) {
        const int rq = wm * 64 + fr * 16 + lr;
        af[fr] = *(const bf16x8*)&slot[rq * 32 + ((g ^ ((rq >> 1) & 3)) << 3)];
        const int rk = wn * 64 + fr * 16 + lr;
        bq[fr] = *(const bf16x8*)&slot[4096 + rk * 32 + ((g ^ ((rk >> 1) & 3)) << 3)];
      }
#pragma unroll
      for (int i = 0; i < 4; ++i)
#pragma unroll
        for (int j = 0; j < 4; ++j)
          st[i][j] = __builtin_amdgcn_mfma_f32_16x16x32_bf16(af[i], bq[j], st[i][j], 0, 0, 0);
      if (c + 2 < NC) {
        asm volatile("s_waitcnt vmcnt(4)" ::: "memory");
        asm volatile("s_barrier" ::: "memory");
      } else if (c + 1 < NC) {
        asm volatile("s_waitcnt vmcnt(0)" ::: "memory");
        asm volatile("s_barrier" ::: "memory");
      }
    }
    const int chq = (b * NHEAD + hc) * SEQ + q0 + wm * 64 + g * 4;
#pragma unroll
    for (int i = 0; i < 4; ++i) {
      const f32x4 cq = *(const f32x4*)&c_s[chq + i * 16];
#pragma unroll
      for (int j = 0; j < 4; ++j)
#pragma unroll
        for (int jr = 0; jr < 4; ++jr)
          acc[i][j][jr] += __builtin_exp2f(st[i][j][jr] - cq[jr]);
    }
  }

#pragma unroll
  for (int i = 0; i < 4; ++i)
#pragma unroll
    for (int jr = 0; jr < 4; ++jr) {
      const size_t rowoff = (size_t)(b * SEQ + q0 + wm * 64 + i * 16 + g * 4 + jr) * SEQ;
#pragma unroll
      for (int j = 0; j < 4; ++j)
        out[rowoff + k0 + wn * 64 + j * 16 + lr] = acc[i][j][jr];
    }
}

// ---------------------------------------------------------------------------
// Fused tail (round-10 measured-best order): blocks 0..511 = output-GEMM
// tiles, 512..1023 = attn_avg tiles.
// ---------------------------------------------------------------------------
__global__ __launch_bounds__(256, 2) void tail_fused(
    const unsigned short* __restrict__ ctx, const unsigned short* __restrict__ wo,
    const float* __restrict__ b_out, float* __restrict__ out,
    const unsigned short* __restrict__ qs, const unsigned short* __restrict__ ks,
    const float* __restrict__ c_s, float* __restrict__ attn_avg) {
  __shared__ __align__(16) unsigned short lds[3 * 8192];
  const int id = blockIdx.x;
  if (id < 512) {
    gemm_body(lds, ctx, wo, EMBD, (id >> 4) * 128, (id & 15) * 128, EpiOut{b_out, out});
  } else {
    attn_avg_body(lds, qs, ks, c_s, attn_avg, id - 512);
  }
}

// ---------------------------------------------------------------------------
// Flash attention fwd v3 (round-8 proven). Grid: B*H*(SEQ/128) = 512 x 512thr.
// ---------------------------------------------------------------------------
__global__ __launch_bounds__(512, 4) void flash_fwd(
    const unsigned short* __restrict__ qs, const unsigned short* __restrict__ ks,
    const unsigned short* __restrict__ vti, unsigned short* __restrict__ ctx,
    float* __restrict__ c_s) {
  __shared__ __align__(16) unsigned short smem[32768];  // 2 bufs x (K 16KB + V^T 16KB)
  const int tid = threadIdx.x, w = tid >> 6, lane = tid & 63;
  const int g = lane >> 4, lr = lane & 15;
  const int blk = ((int)blockIdx.x & 7) * ((int)gridDim.x >> 3) + ((int)blockIdx.x >> 3);
  const int qt = blk & 15, h = (blk >> 4) & 15, b = blk >> 8;
  const int q0 = qt * 128;
  const size_t bh = ((size_t)(b * NHEAD + h)) * SEQ * HDIM;

  const int qrow = q0 + w * 16 + lr;
  bf16x8 qf[4];
#pragma unroll
  for (int kk = 0; kk < 4; ++kk)
    qf[kk] = *(const bf16x8*)(qs + bh + (size_t)qrow * HDIM + kk * 32 + g * 8);

  float m_run = -1e30f, l_run = 0.f;
  f32x4 o[8] = {};

  auto stage = [&](int buf, int t) {
    unsigned short* kt = smem + buf * 16384;
    unsigned short* vt = kt + 8192;
    const int key0 = t * 64;
#pragma unroll
    for (int c = 0; c < 2; ++c) {
      const int chunk = w * 2 + c;
      const int key = chunk * 4 + (lane >> 4);
      const int slot = lane & 15;
      gload_lds16(ks + bh + (size_t)(key0 + key) * HDIM + ((slot ^ (key & 7)) * 8),
                  &kt[chunk * 512]);
    }
#pragma unroll
    for (int c = 0; c < 2; ++c) {
      const int chunk = w * 2 + c;
      const int d = chunk * 8 + (lane >> 3);
      const int slot = lane & 7;
      gload_lds16(vti + bh + (size_t)d * SEQ + key0 + ((slot ^ (d & 7)) * 8),
                  &vt[chunk * 512]);
    }
  };

  stage(0, 0);
  asm volatile("s_waitcnt vmcnt(0)" ::: "memory");
  __syncthreads();
  int cur = 0;

  for (int t = 0; t < 32; ++t) {
    if (t + 1 < 32) stage(cur ^ 1, t + 1);
    const unsigned short* kt = smem + cur * 16384;
    const unsigned short* vt = kt + 8192;

    f32x4 st[4] = {};
    __builtin_amdgcn_s_setprio(1);
#pragma unroll
    for (int kk = 0; kk < 4; ++kk)
#pragma unroll
      for (int fc = 0; fc < 4; ++fc) {
        const int key = fc * 16 + lr;
        bf16x8 kf = *(const bf16x8*)&kt[key * 128 + (((kk * 4 + g) ^ (key & 7)) << 3)];
        st[fc] = __builtin_amdgcn_mfma_f32_16x16x32_bf16(kf, qf[kk], st[fc], 0, 0, 0);
      }
    __builtin_amdgcn_s_setprio(0);

    float tmax = st[0][0];
#pragma unroll
    for (int fc = 0; fc < 4; ++fc)
#pragma unroll
      for (int j = 0; j < 4; ++j) tmax = fmaxf(tmax, st[fc][j]);
    tmax = fmaxf(tmax, __shfl_xor(tmax, 16));
    tmax = fmaxf(tmax, __shfl_xor(tmax, 32));
    if (!__all(tmax <= m_run + 8.f)) {
      const float m_new = fmaxf(m_run, tmax);
      const float corr = __builtin_exp2f(m_run - m_new);
      l_run *= corr;
#pragma unroll
      for (int fd = 0; fd < 8; ++fd)
#pragma unroll
        for (int j = 0; j < 4; ++j) o[fd][j] *= corr;
      m_run = m_new;
    }
    float pt[4][4];
    float tsum = 0.f;
#pragma unroll
    for (int fc = 0; fc < 4; ++fc)
#pragma unroll
      for (int j = 0; j < 4; ++j) {
        const float e = __builtin_exp2f(st[fc][j] - m_run);
        pt[fc][j] = e; tsum += e;
      }
    tsum += __shfl_xor(tsum, 16);
    tsum += __shfl_xor(tsum, 32);
    l_run += tsum;

    bf16x8 pb[2];
#pragma unroll
    for (int c = 0; c < 2; ++c)
#pragma unroll
      for (int j = 0; j < 4; ++j) {
        pb[c][j]     = f2bfs(pt[2 * c][j]);
        pb[c][4 + j] = f2bfs(pt[2 * c + 1][j]);
      }

    __builtin_amdgcn_s_setprio(1);
#pragma unroll
    for (int fd = 0; fd < 8; ++fd) {
      const int d = fd * 16 + lr;
#pragma unroll
      for (int c = 0; c < 2; ++c) {
        bf16x8 vf = *(const bf16x8*)&vt[d * 64 + (((c * 4 + g) ^ (d & 7)) << 3)];
        o[fd] = __builtin_amdgcn_mfma_f32_16x16x32_bf16(vf, pb[c], o[fd], 0, 0, 0);
      }
    }
    __builtin_amdgcn_s_setprio(0);

    asm volatile("s_waitcnt vmcnt(0)" ::: "memory");
    __syncthreads();
    cur ^= 1;
  }

  const float inv_l = 1.0f / l_run;
  unsigned short* trp = smem + w * 2176;
#pragma unroll
  for (int fd = 0; fd < 8; ++fd)
#pragma unroll
    for (int jp = 0; jp < 2; ++jp) {
      const int d = fd * 16 + 4 * g + 2 * jp;
      unsigned valu = (unsigned)(unsigned short)f2bfs(o[fd][2 * jp] * inv_l) |
                      ((unsigned)(unsigned short)f2bfs(o[fd][2 * jp + 1] * inv_l) << 16);
      *(unsigned*)((char*)trp + lr * 272 + d * 2) = valu;
    }
  __syncthreads();
#pragma unroll
  for (int r4 = 0; r4 < 4; ++r4) {
    const int row = r4 * 4 + g;
    bf16x8 valv = *(const bf16x8*)((char*)trp + row * 272 + lr * 16);
    *(bf16x8*)(ctx + (size_t)(b * SEQ + q0 + w * 16 + row) * EMBD + h * HDIM + lr * 8) = valv;
  }
  if (g == 0) {
    const int ridx = (b * NHEAD + h) * SEQ + q0 + w * 16 + lr;
    c_s[ridx] = m_run + __log2f(l_run) + 4.0f;
  }
}

// ---------------------------------------------------------------------------
extern "C" void kernel_launch(void* const* d_in, const int* in_sizes, int n_in,
                              void* d_out, int out_size, void* d_ws, size_t ws_size,
                              hipStream_t stream) {
  const float* query = (const float*)d_in[0];
  // d_in[1] (key), d_in[2] (value) are ignored by the reference module
  const float* W_in  = (const float*)d_in[3];
  const float* b_in  = (const float*)d_in[4];
  const float* W_out = (const float*)d_in[5];
  const float* b_out = (const float*)d_in[6];

  float* out      = (float*)d_out;                       // [B,L,E]
  float* attn_avg = out + (size_t)BATCH * SEQ * EMBD;    // [B,L,L]

  char* ws = (char*)d_ws;
  auto take = [&](size_t bytes) { char* p = ws; ws += bytes; return p; };
  const size_t szBLE = (size_t)BATCH * SEQ * EMBD * 2;   // bf16 [B*L, E]
  unsigned short* qbf = (unsigned short*)take(szBLE);
  unsigned short* wi  = (unsigned short*)take((size_t)3 * EMBD * EMBD * 2);
  unsigned short* wo  = (unsigned short*)take((size_t)EMBD * EMBD * 2);
  unsigned short* qsb = (unsigned short*)take(szBLE);    // [B,H,L,D] *QSCALE
  unsigned short* ksb = (unsigned short*)take(szBLE);    // [B,H,L,D]
  unsigned short* vti = (unsigned short*)take(szBLE);    // [B,H,D,Lperm]
  unsigned short* ctx = (unsigned short*)take(szBLE);    // [B,L,H,D] == [B*L, E]
  float* c_s = (float*)take((size_t)BATCH * NHEAD * SEQ * 4);

  cvt_bf16_3<<<2048, 256, 0, stream>>>(query, qbf, BATCH * SEQ * EMBD,
                                       W_in, wi, 3 * EMBD * EMBD,
                                       W_out, wo, EMBD * EMBD);

  // qkv = query @ W_in^T + b_in  (M=4096, N=6144, K=2048), 8-phase 256^2
  gemm_qkv8<<<16 * 24, 512, 0, stream>>>(qbf, wi, EpiQKV{b_in, qsb, ksb, vti});
  // attention (writes ctx, c_s)
  flash_fwd<<<BATCH * NHEAD * (SEQ / 128), 512, 0, stream>>>(qsb, ksb, vti, ctx, c_s);
  // fused tail: output GEMM (blocks 0-511) + attn_avg (512-1023)
  tail_fused<<<1024, 256, 0, stream>>>(ctx, wo, b_out, out, qsb, ksb, c_s, attn_avg);
}

// Round 15
// 361.713 us; speedup vs baseline: 1.0548x; 1.0154x over previous
//
#include <hip/hip_runtime.h>
#include <hip/hip_bf16.h>
#include <stdint.h>
#include <stddef.h>

// Problem constants (fixed by the reference)
constexpr int BATCH = 2;
constexpr int SEQ   = 2048;
constexpr int EMBD  = 2048;
constexpr int NHEAD = 16;
constexpr int HDIM  = 128;
// 1/sqrt(128) * log2(e): scores land in log2-domain -> exp2 directly
constexpr float QSCALE = 0.08838834764831845f * 1.4426950408889634f;

typedef short bf16x8 __attribute__((ext_vector_type(8)));
typedef float f32x4  __attribute__((ext_vector_type(4)));

__device__ __forceinline__ short f2bfs(float f) {
  union { __hip_bfloat16 h; short s; } u;
  u.h = __float2bfloat16(f);   // hardware cvt (RNE), pairs fuse to v_cvt_pk_bf16_f32
  return u.s;
}

__device__ __forceinline__ void gload_lds16(const void* g, void* l) {
  __builtin_amdgcn_global_load_lds(
      (const __attribute__((address_space(1))) unsigned int*)g,
      (__attribute__((address_space(3))) unsigned int*)l, 16, 0, 0);
}

// key index -> position within vti's interleaved row (16B slot holds keys
// {32c+4g..+3, 32c+16+4g..+3} so PV A-frags are single b128 reads)
__device__ __forceinline__ int vperm(int k) {
  return (k & ~31) | (k & 3) | (((k >> 4) & 1) << 2) | (((k >> 2) & 3) << 3);
}

// ---------------------------------------------------------------------------
// fp32 -> bf16 cast, query + W_in in one launch (W_out is cast inside gemm1's
// idle second round). G13 vectorized.
// ---------------------------------------------------------------------------
__global__ void cvt_bf16_2(const float* __restrict__ s0, unsigned short* __restrict__ d0, int n0,
                           const float* __restrict__ s1, unsigned short* __restrict__ d1, int n1) {
  int i = (blockIdx.x * blockDim.x + threadIdx.x) * 8;
  const int stride = gridDim.x * blockDim.x * 8;
  const int tot = n0 + n1;
  for (; i < tot; i += stride) {
    const float* s; unsigned short* d; int off;
    if (i < n0) { s = s0; d = d0; off = i; }
    else        { s = s1; d = d1; off = i - n0; }
    float4 a = *(const float4*)(s + off);
    float4 b = *(const float4*)(s + off + 4);
    union { unsigned short u[8]; int4 v; } r;
    r.u[0] = (unsigned short)f2bfs(a.x); r.u[1] = (unsigned short)f2bfs(a.y);
    r.u[2] = (unsigned short)f2bfs(a.z); r.u[3] = (unsigned short)f2bfs(a.w);
    r.u[4] = (unsigned short)f2bfs(b.x); r.u[5] = (unsigned short)f2bfs(b.y);
    r.u[6] = (unsigned short)f2bfs(b.z); r.u[7] = (unsigned short)f2bfs(b.w);
    *(int4*)(d + off) = r.v;
  }
}

// ---------------------------------------------------------------------------
// Epilogues
// ---------------------------------------------------------------------------
struct EpiQKV {
  const float* bias;
  unsigned short* qs; unsigned short* ks; unsigned short* vti;
  __device__ void operator()(int row, int col, float v) const {
    float val = v + bias[col];
    const int which = col >> 11;          // 0:q 1:k 2:v  (block-uniform)
    const int h = (col >> 7) & 15;
    const int d = col & 127;
    const int b = row >> 11, l = row & (SEQ - 1);
    if (which == 0) {
      qs[(((unsigned)(b * NHEAD + h) * SEQ) + l) * HDIM + d] = (unsigned short)f2bfs(val * QSCALE);
    } else if (which == 1) {
      ks[(((unsigned)(b * NHEAD + h) * SEQ) + l) * HDIM + d] = (unsigned short)f2bfs(val);
    } else {
      // V stored pre-transposed + key-interleaved: [B,H,D,SEQperm]
      vti[(((unsigned)(b * NHEAD + h) * HDIM) + d) * SEQ + vperm(l)] = (unsigned short)f2bfs(val);
    }
  }
};

struct EpiOut {
  const float* bias;
  float* out;
  __device__ void operator()(int row, int col, float v) const {
    out[(size_t)row * EMBD + col] = v + bias[col];
  }
};

// ---------------------------------------------------------------------------
// gemm1 (QKV): 256x256 tile, BK=64, 8 waves, 8-phase staggered schedule
// (measured-best: 150 us, FETCH 94 MB, conflicts 0). Grid = 384 GEMM blocks
// + 32 trailing cvt blocks (ids 384-415) that cast W_out fp32->bf16 on the
// CUs idled by the 1.5-round GEMM packing (384 blocks / 256 CUs).
// ---------------------------------------------------------------------------
__global__ __launch_bounds__(512, 2) void gemm_qkv8(
    const unsigned short* __restrict__ A, const unsigned short* __restrict__ B,
    const float* __restrict__ wof, unsigned short* __restrict__ wo,
    EpiQKV epi) {
  __shared__ __align__(16) unsigned short lds[2][32768];
  const int tid = threadIdx.x, w = tid >> 6, lane = tid & 63;
  const int g = lane >> 4, lr = lane & 15;
  const int wm = w >> 2, wn = w & 3;

  if ((int)blockIdx.x >= 384) {
    // ---- W_out cast: 32 blocks x 512 thr, grid-stride over E*E elements.
    // Runs on CUs idled by the GEMM's partial second round. No barriers.
    const int cb = (int)blockIdx.x - 384;
    int i = (cb * 512 + tid) * 8;
    const int stride = 32 * 512 * 8;
    const int n = EMBD * EMBD;
    for (; i < n; i += stride) {
      float4 a = *(const float4*)(wof + i);
      float4 b = *(const float4*)(wof + i + 4);
      union { unsigned short u[8]; int4 v; } r;
      r.u[0] = (unsigned short)f2bfs(a.x); r.u[1] = (unsigned short)f2bfs(a.y);
      r.u[2] = (unsigned short)f2bfs(a.z); r.u[3] = (unsigned short)f2bfs(a.w);
      r.u[4] = (unsigned short)f2bfs(b.x); r.u[5] = (unsigned short)f2bfs(b.y);
      r.u[6] = (unsigned short)f2bfs(b.z); r.u[7] = (unsigned short)f2bfs(b.w);
      *(int4*)(wo + i) = r.v;
    }
    return;
  }

  const int m0 = ((int)blockIdx.x / 24) * 256;
  const int n0 = ((int)blockIdx.x % 24) * 256;
  constexpr int K = 2048;
  constexpr int nt = K / 64;   // 32

  const int srow = tid >> 3, sslot = tid & 7;

  auto stageH = [&](int t, int sel, int hh) {
    const unsigned short* src = sel ? B : A;
    const int base0 = sel ? n0 : m0;
    const int kel = t * 64 + ((sslot ^ (srow & 7)) << 3);
#pragma unroll
    for (int l = 0; l < 2; ++l)
      gload_lds16(src + (size_t)(base0 + hh * 128 + l * 64 + srow) * K + kel,
                  &lds[t & 1][sel * 16384 + hh * 8192 + (l * 512 + tid) * 8]);
  };
  auto rdA = [&](int buf, int Mh, int kk, int fr) -> bf16x8 {
    const int r = Mh * 128 + wm * 64 + fr * 16 + lr;
    return *(const bf16x8*)&lds[buf][r * 64 + (((kk * 4 + g) ^ (r & 7)) << 3)];
  };
  auto rdB = [&](int buf, int Nh, int kk, int fb) -> bf16x8 {
    const int r = Nh * 128 + wn * 32 + fb * 16 + lr;
    return *(const bf16x8*)&lds[buf][16384 + r * 64 + (((kk * 4 + g) ^ (r & 7)) << 3)];
  };

  f32x4 acc[8][4] = {};            // [Mh*4+fr][Nh*2+fb]
  bf16x8 a[4][2], bl[2][2], bh[2][2];

  // prologue: tile 0 fully + tile 1 {A-lo, B-lo, B-hi}
  stageH(0, 0, 0); stageH(0, 0, 1); stageH(0, 1, 0); stageH(0, 1, 1);
  stageH(1, 0, 0); stageH(1, 1, 0); stageH(1, 1, 1);
  asm volatile("s_waitcnt vmcnt(6)" ::: "memory");   // tile 0 landed
  __builtin_amdgcn_s_barrier();

  for (int t = 0; t < nt; ++t) {
    const int buf = t & 1;
    // ---- phase 1: (M0,N0); read A-lo + B-lo; stage t+1.A-hi (other buf)
#pragma unroll
    for (int fr = 0; fr < 4; ++fr) { a[fr][0] = rdA(buf, 0, 0, fr); a[fr][1] = rdA(buf, 0, 1, fr); }
#pragma unroll
    for (int fb = 0; fb < 2; ++fb) { bl[fb][0] = rdB(buf, 0, 0, fb); bl[fb][1] = rdB(buf, 0, 1, fb); }
    if (t + 1 < nt) stageH(t + 1, 0, 1);
    __builtin_amdgcn_s_barrier();
    asm volatile("s_waitcnt lgkmcnt(0)" ::: "memory");
    __builtin_amdgcn_s_setprio(1);
#pragma unroll
    for (int fr = 0; fr < 4; ++fr)
#pragma unroll
      for (int fb = 0; fb < 2; ++fb)
#pragma unroll
        for (int kk = 0; kk < 2; ++kk)
          acc[fr][fb] = __builtin_amdgcn_mfma_f32_16x16x32_bf16(a[fr][kk], bl[fb][kk], acc[fr][fb], 0, 0, 0);
    __builtin_amdgcn_s_setprio(0);
    __builtin_amdgcn_s_barrier();
    // ---- phase 2: (M0,N1); read B-hi; stage t+2.A-lo (current buf, dead)
#pragma unroll
    for (int fb = 0; fb < 2; ++fb) { bh[fb][0] = rdB(buf, 1, 0, fb); bh[fb][1] = rdB(buf, 1, 1, fb); }
    if (t + 2 < nt) stageH(t + 2, 0, 0);
    __builtin_amdgcn_s_barrier();
    asm volatile("s_waitcnt lgkmcnt(0)" ::: "memory");
    __builtin_amdgcn_s_setprio(1);
#pragma unroll
    for (int fr = 0; fr < 4; ++fr)
#pragma unroll
      for (int fb = 0; fb < 2; ++fb)
#pragma unroll
        for (int kk = 0; kk < 2; ++kk)
          acc[fr][2 + fb] = __builtin_amdgcn_mfma_f32_16x16x32_bf16(a[fr][kk], bh[fb][kk], acc[fr][2 + fb], 0, 0, 0);
    __builtin_amdgcn_s_setprio(0);
    __builtin_amdgcn_s_barrier();
    // ---- phase 3: (M1,N1); read A-hi; stage t+2.B-lo (dead since p1)
#pragma unroll
    for (int fr = 0; fr < 4; ++fr) { a[fr][0] = rdA(buf, 1, 0, fr); a[fr][1] = rdA(buf, 1, 1, fr); }
    if (t + 2 < nt) stageH(t + 2, 1, 0);
    __builtin_amdgcn_s_barrier();
    asm volatile("s_waitcnt lgkmcnt(0)" ::: "memory");
    __builtin_amdgcn_s_setprio(1);
#pragma unroll
    for (int fr = 0; fr < 4; ++fr)
#pragma unroll
      for (int fb = 0; fb < 2; ++fb)
#pragma unroll
        for (int kk = 0; kk < 2; ++kk)
          acc[4 + fr][2 + fb] = __builtin_amdgcn_mfma_f32_16x16x32_bf16(a[fr][kk], bh[fb][kk], acc[4 + fr][2 + fb], 0, 0, 0);
    __builtin_amdgcn_s_setprio(0);
    __builtin_amdgcn_s_barrier();
    // ---- phase 4: (M1,N0); no reads (A-hi + B-lo in regs); stage t+2.B-hi
    if (t + 2 < nt) stageH(t + 2, 1, 1);
    __builtin_amdgcn_s_barrier();
    __builtin_amdgcn_s_setprio(1);
#pragma unroll
    for (int fr = 0; fr < 4; ++fr)
#pragma unroll
      for (int fb = 0; fb < 2; ++fb)
#pragma unroll
        for (int kk = 0; kk < 2; ++kk)
          acc[4 + fr][fb] = __builtin_amdgcn_mfma_f32_16x16x32_bf16(a[fr][kk], bl[fb][kk], acc[4 + fr][fb], 0, 0, 0);
    __builtin_amdgcn_s_setprio(0);
    // ---- K-tile boundary: counted vmcnt proves tile t+1 fully landed
    if (t + 2 < nt) {
      asm volatile("s_waitcnt vmcnt(6)" ::: "memory");
    } else if (t + 1 < nt) {
      asm volatile("s_waitcnt vmcnt(0)" ::: "memory");
    }
    __builtin_amdgcn_s_barrier();
  }

  // epilogue: interleaved-quadrant positions
#pragma unroll
  for (int mf = 0; mf < 8; ++mf)
#pragma unroll
    for (int nf = 0; nf < 4; ++nf) {
      const int row = m0 + (mf >> 2) * 128 + wm * 64 + (mf & 3) * 16 + g * 4;
      const int col = n0 + (nf >> 1) * 128 + wn * 32 + (nf & 1) * 16 + lr;
#pragma unroll
      for (int jr = 0; jr < 4; ++jr) epi(row + jr, col, acc[mf][nf][jr]);
    }
}

// ---------------------------------------------------------------------------
// GEMM body (m97 structure, 128x128 tile, BK=32) — kept for the output GEMM
// ---------------------------------------------------------------------------
template <class Epi>
__device__ void gemm_body(unsigned short* ldsbuf,
                          const unsigned short* __restrict__ A,
                          const unsigned short* __restrict__ B,
                          int K, int m0, int n0, Epi epi) {
  const int tid = threadIdx.x;
  const int w = tid >> 6, lane = tid & 63;
  const int g = lane >> 4, lr = lane & 15;
  const int wm = w >> 1, wn = w & 1;
  const int srow = lane >> 2, sslot = lane & 3;

  f32x4 acc[4][4] = {};

  auto stage = [&](int buf, int t) {
    const int k0 = t * 32;
    unsigned short* slot = ldsbuf + buf * 8192;
#pragma unroll
    for (int c2 = 0; c2 < 2; ++c2) {
      const int chunk = 2 * w + c2;
      const int row = chunk * 16 + srow;
      const int kel = k0 + ((sslot ^ ((row >> 1) & 3)) << 3);
      gload_lds16(A + (size_t)(m0 + row) * K + kel, &slot[chunk * 512]);
      gload_lds16(B + (size_t)(n0 + row) * K + kel, &slot[4096 + chunk * 512]);
    }
  };

  const int nt = K >> 5;
  int cur = 0;
  stage(0, 0);
  asm volatile("s_waitcnt vmcnt(0)" ::: "memory");
  __syncthreads();

  for (int t = 0; t < nt; ++t) {
    if (t + 1 < nt) stage(cur ^ 1, t + 1);
    const unsigned short* slot = ldsbuf + cur * 8192;
    bf16x8 af[4], bq[4];
#pragma unroll
    for (int fr = 0; fr < 4; ++fr) {
      const int r = wm * 64 + fr * 16 + lr;
      af[fr] = *(const bf16x8*)&slot[r * 32 + ((g ^ ((r >> 1) & 3)) << 3)];
      const int rn = wn * 64 + fr * 16 + lr;
      bq[fr] = *(const bf16x8*)&slot[4096 + rn * 32 + ((g ^ ((rn >> 1) & 3)) << 3)];
    }
#pragma unroll
    for (int i = 0; i < 4; ++i)
#pragma unroll
      for (int j = 0; j < 4; ++j)
        acc[i][j] = __builtin_amdgcn_mfma_f32_16x16x32_bf16(af[i], bq[j], acc[i][j], 0, 0, 0);
    asm volatile("s_waitcnt vmcnt(0)" ::: "memory");
    __syncthreads();
    cur ^= 1;
  }

#pragma unroll
  for (int i = 0; i < 4; ++i)
#pragma unroll
    for (int j = 0; j < 4; ++j) {
      const int row = m0 + wm * 64 + i * 16 + g * 4;
      const int col = n0 + wn * 64 + j * 16 + lr;
#pragma unroll
      for (int jr = 0; jr < 4; ++jr) epi(row + jr, col, acc[i][j][jr]);
    }
}

// ---------------------------------------------------------------------------
// attn_avg body: grouped-GEMM over heads with ring-3 LDS + counted vmcnt.
// ---------------------------------------------------------------------------
__device__ void attn_avg_body(unsigned short* lds,
                              const unsigned short* __restrict__ qs,
                              const unsigned short* __restrict__ ks,
                              const float* __restrict__ c_s,
                              float* __restrict__ out, int blk) {
  const int tid = threadIdx.x, w = tid >> 6, lane = tid & 63;
  const int g = lane >> 4, lr = lane & 15;
  const int wm = w >> 1, wn = w & 1;
  const int k0 = (blk & 15) * 128, q0 = ((blk >> 4) & 15) * 128, b = blk >> 8;
  const int srow = lane >> 2, sslot = lane & 3;

  constexpr int NC = NHEAD * 4;   // 64 chunks

  auto stage = [&](int c) {
    const size_t bh = ((size_t)(b * NHEAD + (c >> 2))) * SEQ * HDIM + (c & 3) * 32;
    unsigned short* slot = lds + (c % 3) * 8192;
#pragma unroll
    for (int c2 = 0; c2 < 2; ++c2) {
      const int chunk = 2 * w + c2;            // 0..7, 16 rows each
      const int row = chunk * 16 + srow;
      const int kel = (sslot ^ ((row >> 1) & 3)) << 3;
      gload_lds16(qs + bh + (size_t)(q0 + row) * HDIM + kel, &slot[chunk * 512]);
      gload_lds16(ks + bh + (size_t)(k0 + row) * HDIM + kel, &slot[4096 + chunk * 512]);
    }
  };

  f32x4 acc[4][4] = {};

  stage(0); stage(1);
  asm volatile("s_waitcnt vmcnt(4)" ::: "memory");
  asm volatile("s_barrier" ::: "memory");

  for (int hc = 0; hc < NHEAD; ++hc) {
    f32x4 st[4][4] = {};
#pragma unroll
    for (int dq = 0; dq < 4; ++dq) {
      const int c = hc * 4 + dq;
      if (c + 2 < NC) stage(c + 2);
      const unsigned short* slot = lds + (c % 3) * 8192;
      bf16x8 af[4], bq[4];
#pragma unroll
      for (int fr = 0; fr < 4; ++fr) {
        const int rq = wm * 64 + fr * 16 + lr;
        af[fr] = *(const bf16x8*)&slot[rq * 32 + ((g ^ ((rq >> 1) & 3)) << 3)];
        const int rk = wn * 64 + fr * 16 + lr;
        bq[fr] = *(const bf16x8*)&slot[4096 + rk * 32 + ((g ^ ((rk >> 1) & 3)) << 3)];
      }
#pragma unroll
      for (int i = 0; i < 4; ++i)
#pragma unroll
        for (int j = 0; j < 4; ++j)
          st[i][j] = __builtin_amdgcn_mfma_f32_16x16x32_bf16(af[i], bq[j], st[i][j], 0, 0, 0);
      if (c + 2 < NC) {
        asm volatile("s_waitcnt vmcnt(4)" ::: "memory");
        asm volatile("s_barrier" ::: "memory");
      } else if (c + 1 < NC) {
        asm volatile("s_waitcnt vmcnt(0)" ::: "memory");
        asm volatile("s_barrier" ::: "memory");
      }
    }
    const int chq = (b * NHEAD + hc) * SEQ + q0 + wm * 64 + g * 4;
#pragma unroll
    for (int i = 0; i < 4; ++i) {
      const f32x4 cq = *(const f32x4*)&c_s[chq + i * 16];
#pragma unroll
      for (int j = 0; j < 4; ++j)
#pragma unroll
        for (int jr = 0; jr < 4; ++jr)
          acc[i][j][jr] += __builtin_exp2f(st[i][j][jr] - cq[jr]);
    }
  }

#pragma unroll
  for (int i = 0; i < 4; ++i)
#pragma unroll
    for (int jr = 0; jr < 4; ++jr) {
      const size_t rowoff = (size_t)(b * SEQ + q0 + wm * 64 + i * 16 + g * 4 + jr) * SEQ;
#pragma unroll
      for (int j = 0; j < 4; ++j)
        out[rowoff + k0 + wn * 64 + j * 16 + lr] = acc[i][j][jr];
    }
}

// ---------------------------------------------------------------------------
// Fused tail (measured-best order): blocks 0..511 = output-GEMM tiles,
// 512..1023 = attn_avg tiles.
// ---------------------------------------------------------------------------
__global__ __launch_bounds__(256, 2) void tail_fused(
    const unsigned short* __restrict__ ctx, const unsigned short* __restrict__ wo,
    const float* __restrict__ b_out, float* __restrict__ out,
    const unsigned short* __restrict__ qs, const unsigned short* __restrict__ ks,
    const float* __restrict__ c_s, float* __restrict__ attn_avg) {
  __shared__ __align__(16) unsigned short lds[3 * 8192];
  const int id = blockIdx.x;
  if (id < 512) {
    gemm_body(lds, ctx, wo, EMBD, (id >> 4) * 128, (id & 15) * 128, EpiOut{b_out, out});
  } else {
    attn_avg_body(lds, qs, ks, c_s, attn_avg, id - 512);
  }
}

// ---------------------------------------------------------------------------
// Flash attention fwd v3 (round-8 proven). Grid: B*H*(SEQ/128) = 512 x 512thr.
// ---------------------------------------------------------------------------
__global__ __launch_bounds__(512, 4) void flash_fwd(
    const unsigned short* __restrict__ qs, const unsigned short* __restrict__ ks,
    const unsigned short* __restrict__ vti, unsigned short* __restrict__ ctx,
    float* __restrict__ c_s) {
  __shared__ __align__(16) unsigned short smem[32768];  // 2 bufs x (K 16KB + V^T 16KB)
  const int tid = threadIdx.x, w = tid >> 6, lane = tid & 63;
  const int g = lane >> 4, lr = lane & 15;
  const int blk = ((int)blockIdx.x & 7) * ((int)gridDim.x >> 3) + ((int)blockIdx.x >> 3);
  const int qt = blk & 15, h = (blk >> 4) & 15, b = blk >> 8;
  const int q0 = qt * 128;
  const size_t bh = ((size_t)(b * NHEAD + h)) * SEQ * HDIM;

  const int qrow = q0 + w * 16 + lr;
  bf16x8 qf[4];
#pragma unroll
  for (int kk = 0; kk < 4; ++kk)
    qf[kk] = *(const bf16x8*)(qs + bh + (size_t)qrow * HDIM + kk * 32 + g * 8);

  float m_run = -1e30f, l_run = 0.f;
  f32x4 o[8] = {};

  auto stage = [&](int buf, int t) {
    unsigned short* kt = smem + buf * 16384;
    unsigned short* vt = kt + 8192;
    const int key0 = t * 64;
#pragma unroll
    for (int c = 0; c < 2; ++c) {
      const int chunk = w * 2 + c;
      const int key = chunk * 4 + (lane >> 4);
      const int slot = lane & 15;
      gload_lds16(ks + bh + (size_t)(key0 + key) * HDIM + ((slot ^ (key & 7)) * 8),
                  &kt[chunk * 512]);
    }
#pragma unroll
    for (int c = 0; c < 2; ++c) {
      const int chunk = w * 2 + c;
      const int d = chunk * 8 + (lane >> 3);
      const int slot = lane & 7;
      gload_lds16(vti + bh + (size_t)d * SEQ + key0 + ((slot ^ (d & 7)) * 8),
                  &vt[chunk * 512]);
    }
  };

  stage(0, 0);
  asm volatile("s_waitcnt vmcnt(0)" ::: "memory");
  __syncthreads();
  int cur = 0;

  for (int t = 0; t < 32; ++t) {
    if (t + 1 < 32) stage(cur ^ 1, t + 1);
    const unsigned short* kt = smem + cur * 16384;
    const unsigned short* vt = kt + 8192;

    f32x4 st[4] = {};
    __builtin_amdgcn_s_setprio(1);
#pragma unroll
    for (int kk = 0; kk < 4; ++kk)
#pragma unroll
      for (int fc = 0; fc < 4; ++fc) {
        const int key = fc * 16 + lr;
        bf16x8 kf = *(const bf16x8*)&kt[key * 128 + (((kk * 4 + g) ^ (key & 7)) << 3)];
        st[fc] = __builtin_amdgcn_mfma_f32_16x16x32_bf16(kf, qf[kk], st[fc], 0, 0, 0);
      }
    __builtin_amdgcn_s_setprio(0);

    float tmax = st[0][0];
#pragma unroll
    for (int fc = 0; fc < 4; ++fc)
#pragma unroll
      for (int j = 0; j < 4; ++j) tmax = fmaxf(tmax, st[fc][j]);
    tmax = fmaxf(tmax, __shfl_xor(tmax, 16));
    tmax = fmaxf(tmax, __shfl_xor(tmax, 32));
    if (!__all(tmax <= m_run + 8.f)) {
      const float m_new = fmaxf(m_run, tmax);
      const float corr = __builtin_exp2f(m_run - m_new);
      l_run *= corr;
#pragma unroll
      for (int fd = 0; fd < 8; ++fd)
#pragma unroll
        for (int j = 0; j < 4; ++j) o[fd][j] *= corr;
      m_run = m_new;
    }
    float pt[4][4];
    float tsum = 0.f;
#pragma unroll
    for (int fc = 0; fc < 4; ++fc)
#pragma unroll
      for (int j = 0; j < 4; ++j) {
        const float e = __builtin_exp2f(st[fc][j] - m_run);
        pt[fc][j] = e; tsum += e;
      }
    tsum += __shfl_xor(tsum, 16);
    tsum += __shfl_xor(tsum, 32);
    l_run += tsum;

    bf16x8 pb[2];
#pragma unroll
    for (int c = 0; c < 2; ++c)
#pragma unroll
      for (int j = 0; j < 4; ++j) {
        pb[c][j]     = f2bfs(pt[2 * c][j]);
        pb[c][4 + j] = f2bfs(pt[2 * c + 1][j]);
      }

    __builtin_amdgcn_s_setprio(1);
#pragma unroll
    for (int fd = 0; fd < 8; ++fd) {
      const int d = fd * 16 + lr;
#pragma unroll
      for (int c = 0; c < 2; ++c) {
        bf16x8 vf = *(const bf16x8*)&vt[d * 64 + (((c * 4 + g) ^ (d & 7)) << 3)];
        o[fd] = __builtin_amdgcn_mfma_f32_16x16x32_bf16(vf, pb[c], o[fd], 0, 0, 0);
      }
    }
    __builtin_amdgcn_s_setprio(0);

    asm volatile("s_waitcnt vmcnt(0)" ::: "memory");
    __syncthreads();
    cur ^= 1;
  }

  const float inv_l = 1.0f / l_run;
  unsigned short* trp = smem + w * 2176;
#pragma unroll
  for (int fd = 0; fd < 8; ++fd)
#pragma unroll
    for (int jp = 0; jp < 2; ++jp) {
      const int d = fd * 16 + 4 * g + 2 * jp;
      unsigned valu = (unsigned)(unsigned short)f2bfs(o[fd][2 * jp] * inv_l) |
                      ((unsigned)(unsigned short)f2bfs(o[fd][2 * jp + 1] * inv_l) << 16);
      *(unsigned*)((char*)trp + lr * 272 + d * 2) = valu;
    }
  __syncthreads();
#pragma unroll
  for (int r4 = 0; r4 < 4; ++r4) {
    const int row = r4 * 4 + g;
    bf16x8 valv = *(const bf16x8*)((char*)trp + row * 272 + lr * 16);
    *(bf16x8*)(ctx + (size_t)(b * SEQ + q0 + w * 16 + row) * EMBD + h * HDIM + lr * 8) = valv;
  }
  if (g == 0) {
    const int ridx = (b * NHEAD + h) * SEQ + q0 + w * 16 + lr;
    c_s[ridx] = m_run + __log2f(l_run) + 4.0f;
  }
}

// ---------------------------------------------------------------------------
extern "C" void kernel_launch(void* const* d_in, const int* in_sizes, int n_in,
                              void* d_out, int out_size, void* d_ws, size_t ws_size,
                              hipStream_t stream) {
  const float* query = (const float*)d_in[0];
  // d_in[1] (key), d_in[2] (value) are ignored by the reference module
  const float* W_in  = (const float*)d_in[3];
  const float* b_in  = (const float*)d_in[4];
  const float* W_out = (const float*)d_in[5];
  const float* b_out = (const float*)d_in[6];

  float* out      = (float*)d_out;                       // [B,L,E]
  float* attn_avg = out + (size_t)BATCH * SEQ * EMBD;    // [B,L,L]

  char* ws = (char*)d_ws;
  auto take = [&](size_t bytes) { char* p = ws; ws += bytes; return p; };
  const size_t szBLE = (size_t)BATCH * SEQ * EMBD * 2;   // bf16 [B*L, E]
  unsigned short* qbf = (unsigned short*)take(szBLE);
  unsigned short* wi  = (unsigned short*)take((size_t)3 * EMBD * EMBD * 2);
  unsigned short* wo  = (unsigned short*)take((size_t)EMBD * EMBD * 2);
  unsigned short* qsb = (unsigned short*)take(szBLE);    // [B,H,L,D] *QSCALE
  unsigned short* ksb = (unsigned short*)take(szBLE);    // [B,H,L,D]
  unsigned short* vti = (unsigned short*)take(szBLE);    // [B,H,D,Lperm]
  unsigned short* ctx = (unsigned short*)take(szBLE);    // [B,L,H,D] == [B*L, E]
  float* c_s = (float*)take((size_t)BATCH * NHEAD * SEQ * 4);

  // cast query + W_in (W_out is cast by gemm_qkv8's trailing blocks)
  cvt_bf16_2<<<2048, 256, 0, stream>>>(query, qbf, BATCH * SEQ * EMBD,
                                       W_in, wi, 3 * EMBD * EMBD);

  // qkv = query @ W_in^T + b_in  (M=4096, N=6144, K=2048), 8-phase 256^2;
  // +32 trailing blocks cast W_out on the idle half-round
  gemm_qkv8<<<16 * 24 + 32, 512, 0, stream>>>(qbf, wi, W_out, wo,
                                              EpiQKV{b_in, qsb, ksb, vti});
  // attention (writes ctx, c_s)
  flash_fwd<<<BATCH * NHEAD * (SEQ / 128), 512, 0, stream>>>(qsb, ksb, vti, ctx, c_s);
  // fused tail: output GEMM (blocks 0-511) + attn_avg (512-1023)
  tail_fused<<<1024, 256, 0, stream>>>(ctx, wo, b_out, out, qsb, ksb, c_s, attn_avg);
}

// Round 16
// 361.286 us; speedup vs baseline: 1.0560x; 1.0012x over previous
//
#include <hip/hip_runtime.h>
#include <hip/hip_bf16.h>
#include <stdint.h>
#include <stddef.h>

// Problem constants (fixed by the reference)
constexpr int BATCH = 2;
constexpr int SEQ   = 2048;
constexpr int EMBD  = 2048;
constexpr int NHEAD = 16;
constexpr int HDIM  = 128;
// 1/sqrt(128) * log2(e): scores land in log2-domain -> exp2 directly
constexpr float QSCALE = 0.08838834764831845f * 1.4426950408889634f;

typedef short bf16x8 __attribute__((ext_vector_type(8)));
typedef float f32x4  __attribute__((ext_vector_type(4)));

__device__ __forceinline__ short f2bfs(float f) {
  union { __hip_bfloat16 h; short s; } u;
  u.h = __float2bfloat16(f);   // hardware cvt (RNE), pairs fuse to v_cvt_pk_bf16_f32
  return u.s;
}

__device__ __forceinline__ void gload_lds16(const void* g, void* l) {
  __builtin_amdgcn_global_load_lds(
      (const __attribute__((address_space(1))) unsigned int*)g,
      (__attribute__((address_space(3))) unsigned int*)l, 16, 0, 0);
}

// key index -> position within vti's interleaved row (16B slot holds keys
// {32c+4g..+3, 32c+16+4g..+3} so PV A-frags are single b128 reads)
__device__ __forceinline__ int vperm(int k) {
  return (k & ~31) | (k & 3) | (((k >> 4) & 1) << 2) | (((k >> 2) & 3) << 3);
}

// ---------------------------------------------------------------------------
// fp32 -> bf16 cast, query + W_in in one launch (W_out is cast inside gemm1's
// idle second round). G13 vectorized.
// ---------------------------------------------------------------------------
__global__ void cvt_bf16_2(const float* __restrict__ s0, unsigned short* __restrict__ d0, int n0,
                           const float* __restrict__ s1, unsigned short* __restrict__ d1, int n1) {
  int i = (blockIdx.x * blockDim.x + threadIdx.x) * 8;
  const int stride = gridDim.x * blockDim.x * 8;
  const int tot = n0 + n1;
  for (; i < tot; i += stride) {
    const float* s; unsigned short* d; int off;
    if (i < n0) { s = s0; d = d0; off = i; }
    else        { s = s1; d = d1; off = i - n0; }
    float4 a = *(const float4*)(s + off);
    float4 b = *(const float4*)(s + off + 4);
    union { unsigned short u[8]; int4 v; } r;
    r.u[0] = (unsigned short)f2bfs(a.x); r.u[1] = (unsigned short)f2bfs(a.y);
    r.u[2] = (unsigned short)f2bfs(a.z); r.u[3] = (unsigned short)f2bfs(a.w);
    r.u[4] = (unsigned short)f2bfs(b.x); r.u[5] = (unsigned short)f2bfs(b.y);
    r.u[6] = (unsigned short)f2bfs(b.z); r.u[7] = (unsigned short)f2bfs(b.w);
    *(int4*)(d + off) = r.v;
  }
}

// ---------------------------------------------------------------------------
// Epilogues
// ---------------------------------------------------------------------------
struct EpiQKV {
  const float* bias;
  unsigned short* qs; unsigned short* ks; unsigned short* vti;
  __device__ void operator()(int row, int col, float v) const {
    float val = v + bias[col];
    const int which = col >> 11;          // 0:q 1:k 2:v  (block-uniform)
    const int h = (col >> 7) & 15;
    const int d = col & 127;
    const int b = row >> 11, l = row & (SEQ - 1);
    if (which == 0) {
      qs[(((unsigned)(b * NHEAD + h) * SEQ) + l) * HDIM + d] = (unsigned short)f2bfs(val * QSCALE);
    } else if (which == 1) {
      ks[(((unsigned)(b * NHEAD + h) * SEQ) + l) * HDIM + d] = (unsigned short)f2bfs(val);
    } else {
      // V stored pre-transposed + key-interleaved: [B,H,D,SEQperm]
      vti[(((unsigned)(b * NHEAD + h) * HDIM) + d) * SEQ + vperm(l)] = (unsigned short)f2bfs(val);
    }
  }
};

struct EpiOut {
  const float* bias;
  float* out;
  __device__ void operator()(int row, int col, float v) const {
    out[(size_t)row * EMBD + col] = v + bias[col];
  }
};

// ---------------------------------------------------------------------------
// gemm1 (QKV): 256x256 tile, BK=64, 8 waves, 8-phase staggered schedule
// (measured-best: 150 us, FETCH ~102 MB, conflicts 0). Grid = 384 GEMM blocks
// + 32 trailing cvt blocks (ids 384-415) that cast W_out fp32->bf16 on the
// CUs idled by the 1.5-round GEMM packing (384 blocks / 256 CUs).
// ---------------------------------------------------------------------------
__global__ __launch_bounds__(512, 2) void gemm_qkv8(
    const unsigned short* __restrict__ A, const unsigned short* __restrict__ B,
    const float* __restrict__ wof, unsigned short* __restrict__ wo,
    EpiQKV epi) {
  __shared__ __align__(16) unsigned short lds[2][32768];
  const int tid = threadIdx.x, w = tid >> 6, lane = tid & 63;
  const int g = lane >> 4, lr = lane & 15;
  const int wm = w >> 2, wn = w & 3;

  if ((int)blockIdx.x >= 384) {
    // ---- W_out cast: 32 blocks x 512 thr, grid-stride over E*E elements.
    // Runs on CUs idled by the GEMM's partial second round. No barriers.
    const int cb = (int)blockIdx.x - 384;
    int i = (cb * 512 + tid) * 8;
    const int stride = 32 * 512 * 8;
    const int n = EMBD * EMBD;
    for (; i < n; i += stride) {
      float4 a = *(const float4*)(wof + i);
      float4 b = *(const float4*)(wof + i + 4);
      union { unsigned short u[8]; int4 v; } r;
      r.u[0] = (unsigned short)f2bfs(a.x); r.u[1] = (unsigned short)f2bfs(a.y);
      r.u[2] = (unsigned short)f2bfs(a.z); r.u[3] = (unsigned short)f2bfs(a.w);
      r.u[4] = (unsigned short)f2bfs(b.x); r.u[5] = (unsigned short)f2bfs(b.y);
      r.u[6] = (unsigned short)f2bfs(b.z); r.u[7] = (unsigned short)f2bfs(b.w);
      *(int4*)(wo + i) = r.v;
    }
    return;
  }

  const int m0 = ((int)blockIdx.x / 24) * 256;
  const int n0 = ((int)blockIdx.x % 24) * 256;
  constexpr int K = 2048;
  constexpr int nt = K / 64;   // 32

  const int srow = tid >> 3, sslot = tid & 7;

  auto stageH = [&](int t, int sel, int hh) {
    const unsigned short* src = sel ? B : A;
    const int base0 = sel ? n0 : m0;
    const int kel = t * 64 + ((sslot ^ (srow & 7)) << 3);
#pragma unroll
    for (int l = 0; l < 2; ++l)
      gload_lds16(src + (size_t)(base0 + hh * 128 + l * 64 + srow) * K + kel,
                  &lds[t & 1][sel * 16384 + hh * 8192 + (l * 512 + tid) * 8]);
  };
  auto rdA = [&](int buf, int Mh, int kk, int fr) -> bf16x8 {
    const int r = Mh * 128 + wm * 64 + fr * 16 + lr;
    return *(const bf16x8*)&lds[buf][r * 64 + (((kk * 4 + g) ^ (r & 7)) << 3)];
  };
  auto rdB = [&](int buf, int Nh, int kk, int fb) -> bf16x8 {
    const int r = Nh * 128 + wn * 32 + fb * 16 + lr;
    return *(const bf16x8*)&lds[buf][16384 + r * 64 + (((kk * 4 + g) ^ (r & 7)) << 3)];
  };

  f32x4 acc[8][4] = {};            // [Mh*4+fr][Nh*2+fb]
  bf16x8 a[4][2], bl[2][2], bh[2][2];

  // prologue: tile 0 fully + tile 1 {A-lo, B-lo, B-hi}
  stageH(0, 0, 0); stageH(0, 0, 1); stageH(0, 1, 0); stageH(0, 1, 1);
  stageH(1, 0, 0); stageH(1, 1, 0); stageH(1, 1, 1);
  asm volatile("s_waitcnt vmcnt(6)" ::: "memory");   // tile 0 landed
  __builtin_amdgcn_s_barrier();

  for (int t = 0; t < nt; ++t) {
    const int buf = t & 1;
    // ---- phase 1: (M0,N0); read A-lo + B-lo; stage t+1.A-hi (other buf)
#pragma unroll
    for (int fr = 0; fr < 4; ++fr) { a[fr][0] = rdA(buf, 0, 0, fr); a[fr][1] = rdA(buf, 0, 1, fr); }
#pragma unroll
    for (int fb = 0; fb < 2; ++fb) { bl[fb][0] = rdB(buf, 0, 0, fb); bl[fb][1] = rdB(buf, 0, 1, fb); }
    if (t + 1 < nt) stageH(t + 1, 0, 1);
    __builtin_amdgcn_s_barrier();
    asm volatile("s_waitcnt lgkmcnt(0)" ::: "memory");
    __builtin_amdgcn_s_setprio(1);
#pragma unroll
    for (int fr = 0; fr < 4; ++fr)
#pragma unroll
      for (int fb = 0; fb < 2; ++fb)
#pragma unroll
        for (int kk = 0; kk < 2; ++kk)
          acc[fr][fb] = __builtin_amdgcn_mfma_f32_16x16x32_bf16(a[fr][kk], bl[fb][kk], acc[fr][fb], 0, 0, 0);
    __builtin_amdgcn_s_setprio(0);
    __builtin_amdgcn_s_barrier();
    // ---- phase 2: (M0,N1); read B-hi; stage t+2.A-lo (current buf, dead)
#pragma unroll
    for (int fb = 0; fb < 2; ++fb) { bh[fb][0] = rdB(buf, 1, 0, fb); bh[fb][1] = rdB(buf, 1, 1, fb); }
    if (t + 2 < nt) stageH(t + 2, 0, 0);
    __builtin_amdgcn_s_barrier();
    asm volatile("s_waitcnt lgkmcnt(0)" ::: "memory");
    __builtin_amdgcn_s_setprio(1);
#pragma unroll
    for (int fr = 0; fr < 4; ++fr)
#pragma unroll
      for (int fb = 0; fb < 2; ++fb)
#pragma unroll
        for (int kk = 0; kk < 2; ++kk)
          acc[fr][2 + fb] = __builtin_amdgcn_mfma_f32_16x16x32_bf16(a[fr][kk], bh[fb][kk], acc[fr][2 + fb], 0, 0, 0);
    __builtin_amdgcn_s_setprio(0);
    __builtin_amdgcn_s_barrier();
    // ---- phase 3: (M1,N1); read A-hi; stage t+2.B-lo (dead since p1)
#pragma unroll
    for (int fr = 0; fr < 4; ++fr) { a[fr][0] = rdA(buf, 1, 0, fr); a[fr][1] = rdA(buf, 1, 1, fr); }
    if (t + 2 < nt) stageH(t + 2, 1, 0);
    __builtin_amdgcn_s_barrier();
    asm volatile("s_waitcnt lgkmcnt(0)" ::: "memory");
    __builtin_amdgcn_s_setprio(1);
#pragma unroll
    for (int fr = 0; fr < 4; ++fr)
#pragma unroll
      for (int fb = 0; fb < 2; ++fb)
#pragma unroll
        for (int kk = 0; kk < 2; ++kk)
          acc[4 + fr][2 + fb] = __builtin_amdgcn_mfma_f32_16x16x32_bf16(a[fr][kk], bh[fb][kk], acc[4 + fr][2 + fb], 0, 0, 0);
    __builtin_amdgcn_s_setprio(0);
    __builtin_amdgcn_s_barrier();
    // ---- phase 4: (M1,N0); no reads (A-hi + B-lo in regs); stage t+2.B-hi
    if (t + 2 < nt) stageH(t + 2, 1, 1);
    __builtin_amdgcn_s_barrier();
    __builtin_amdgcn_s_setprio(1);
#pragma unroll
    for (int fr = 0; fr < 4; ++fr)
#pragma unroll
      for (int fb = 0; fb < 2; ++fb)
#pragma unroll
        for (int kk = 0; kk < 2; ++kk)
          acc[4 + fr][fb] = __builtin_amdgcn_mfma_f32_16x16x32_bf16(a[fr][kk], bl[fb][kk], acc[4 + fr][fb], 0, 0, 0);
    __builtin_amdgcn_s_setprio(0);
    // ---- K-tile boundary: counted vmcnt proves tile t+1 fully landed
    if (t + 2 < nt) {
      asm volatile("s_waitcnt vmcnt(6)" ::: "memory");
    } else if (t + 1 < nt) {
      asm volatile("s_waitcnt vmcnt(0)" ::: "memory");
    }
    __builtin_amdgcn_s_barrier();
  }

  // epilogue: interleaved-quadrant positions
#pragma unroll
  for (int mf = 0; mf < 8; ++mf)
#pragma unroll
    for (int nf = 0; nf < 4; ++nf) {
      const int row = m0 + (mf >> 2) * 128 + wm * 64 + (mf & 3) * 16 + g * 4;
      const int col = n0 + (nf >> 1) * 128 + wn * 32 + (nf & 1) * 16 + lr;
#pragma unroll
      for (int jr = 0; jr < 4; ++jr) epi(row + jr, col, acc[mf][nf][jr]);
    }
}

// ---------------------------------------------------------------------------
// GEMM body (m97 structure, 128x128 tile, BK=32) — kept for the output GEMM
// ---------------------------------------------------------------------------
template <class Epi>
__device__ void gemm_body(unsigned short* ldsbuf,
                          const unsigned short* __restrict__ A,
                          const unsigned short* __restrict__ B,
                          int K, int m0, int n0, Epi epi) {
  const int tid = threadIdx.x;
  const int w = tid >> 6, lane = tid & 63;
  const int g = lane >> 4, lr = lane & 15;
  const int wm = w >> 1, wn = w & 1;
  const int srow = lane >> 2, sslot = lane & 3;

  f32x4 acc[4][4] = {};

  auto stage = [&](int buf, int t) {
    const int k0 = t * 32;
    unsigned short* slot = ldsbuf + buf * 8192;
#pragma unroll
    for (int c2 = 0; c2 < 2; ++c2) {
      const int chunk = 2 * w + c2;
      const int row = chunk * 16 + srow;
      const int kel = k0 + ((sslot ^ ((row >> 1) & 3)) << 3);
      gload_lds16(A + (size_t)(m0 + row) * K + kel, &slot[chunk * 512]);
      gload_lds16(B + (size_t)(n0 + row) * K + kel, &slot[4096 + chunk * 512]);
    }
  };

  const int nt = K >> 5;
  int cur = 0;
  stage(0, 0);
  asm volatile("s_waitcnt vmcnt(0)" ::: "memory");
  __syncthreads();

  for (int t = 0; t < nt; ++t) {
    if (t + 1 < nt) stage(cur ^ 1, t + 1);
    const unsigned short* slot = ldsbuf + cur * 8192;
    bf16x8 af[4], bq[4];
#pragma unroll
    for (int fr = 0; fr < 4; ++fr) {
      const int r = wm * 64 + fr * 16 + lr;
      af[fr] = *(const bf16x8*)&slot[r * 32 + ((g ^ ((r >> 1) & 3)) << 3)];
      const int rn = wn * 64 + fr * 16 + lr;
      bq[fr] = *(const bf16x8*)&slot[4096 + rn * 32 + ((g ^ ((rn >> 1) & 3)) << 3)];
    }
#pragma unroll
    for (int i = 0; i < 4; ++i)
#pragma unroll
      for (int j = 0; j < 4; ++j)
        acc[i][j] = __builtin_amdgcn_mfma_f32_16x16x32_bf16(af[i], bq[j], acc[i][j], 0, 0, 0);
    asm volatile("s_waitcnt vmcnt(0)" ::: "memory");
    __syncthreads();
    cur ^= 1;
  }

#pragma unroll
  for (int i = 0; i < 4; ++i)
#pragma unroll
    for (int j = 0; j < 4; ++j) {
      const int row = m0 + wm * 64 + i * 16 + g * 4;
      const int col = n0 + wn * 64 + j * 16 + lr;
#pragma unroll
      for (int jr = 0; jr < 4; ++jr) epi(row + jr, col, acc[i][j][jr]);
    }
}

// ---------------------------------------------------------------------------
// attn_avg body: grouped-GEMM over heads with ring-3 LDS + counted vmcnt.
// ---------------------------------------------------------------------------
__device__ void attn_avg_body(unsigned short* lds,
                              const unsigned short* __restrict__ qs,
                              const unsigned short* __restrict__ ks,
                              const float* __restrict__ c_s,
                              float* __restrict__ out, int blk) {
  const int tid = threadIdx.x, w = tid >> 6, lane = tid & 63;
  const int g = lane >> 4, lr = lane & 15;
  const int wm = w >> 1, wn = w & 1;
  const int k0 = (blk & 15) * 128, q0 = ((blk >> 4) & 15) * 128, b = blk >> 8;
  const int srow = lane >> 2, sslot = lane & 3;

  constexpr int NC = NHEAD * 4;   // 64 chunks

  auto stage = [&](int c) {
    const size_t bh = ((size_t)(b * NHEAD + (c >> 2))) * SEQ * HDIM + (c & 3) * 32;
    unsigned short* slot = lds + (c % 3) * 8192;
#pragma unroll
    for (int c2 = 0; c2 < 2; ++c2) {
      const int chunk = 2 * w + c2;            // 0..7, 16 rows each
      const int row = chunk * 16 + srow;
      const int kel = (sslot ^ ((row >> 1) & 3)) << 3;
      gload_lds16(qs + bh + (size_t)(q0 + row) * HDIM + kel, &slot[chunk * 512]);
      gload_lds16(ks + bh + (size_t)(k0 + row) * HDIM + kel, &slot[4096 + chunk * 512]);
    }
  };

  f32x4 acc[4][4] = {};

  stage(0); stage(1);
  asm volatile("s_waitcnt vmcnt(4)" ::: "memory");
  asm volatile("s_barrier" ::: "memory");

  for (int hc = 0; hc < NHEAD; ++hc) {
    f32x4 st[4][4] = {};
#pragma unroll
    for (int dq = 0; dq < 4; ++dq) {
      const int c = hc * 4 + dq;
      if (c + 2 < NC) stage(c + 2);
      const unsigned short* slot = lds + (c % 3) * 8192;
      bf16x8 af[4], bq[4];
#pragma unroll
      for (int fr = 0; fr < 4; ++fr) {
        const int rq = wm * 64 + fr * 16 + lr;
        af[fr] = *(const bf16x8*)&slot[rq * 32 + ((g ^ ((rq >> 1) & 3)) << 3)];
        const int rk = wn * 64 + fr * 16 + lr;
        bq[fr] = *(const bf16x8*)&slot[4096 + rk * 32 + ((g ^ ((rk >> 1) & 3)) << 3)];
      }
#pragma unroll
      for (int i = 0; i < 4; ++i)
#pragma unroll
        for (int j = 0; j < 4; ++j)
          st[i][j] = __builtin_amdgcn_mfma_f32_16x16x32_bf16(af[i], bq[j], st[i][j], 0, 0, 0);
      if (c + 2 < NC) {
        asm volatile("s_waitcnt vmcnt(4)" ::: "memory");
        asm volatile("s_barrier" ::: "memory");
      } else if (c + 1 < NC) {
        asm volatile("s_waitcnt vmcnt(0)" ::: "memory");
        asm volatile("s_barrier" ::: "memory");
      }
    }
    const int chq = (b * NHEAD + hc) * SEQ + q0 + wm * 64 + g * 4;
#pragma unroll
    for (int i = 0; i < 4; ++i) {
      const f32x4 cq = *(const f32x4*)&c_s[chq + i * 16];
#pragma unroll
      for (int j = 0; j < 4; ++j)
#pragma unroll
        for (int jr = 0; jr < 4; ++jr)
          acc[i][j][jr] += __builtin_exp2f(st[i][j][jr] - cq[jr]);
    }
  }

#pragma unroll
  for (int i = 0; i < 4; ++i)
#pragma unroll
    for (int jr = 0; jr < 4; ++jr) {
      const size_t rowoff = (size_t)(b * SEQ + q0 + wm * 64 + i * 16 + g * 4 + jr) * SEQ;
#pragma unroll
      for (int j = 0; j < 4; ++j)
        out[rowoff + k0 + wn * 64 + j * 16 + lr] = acc[i][j][jr];
    }
}

// ---------------------------------------------------------------------------
// Fused tail (measured-best order): blocks 0..511 = output-GEMM tiles,
// 512..1023 = attn_avg tiles.
// ---------------------------------------------------------------------------
__global__ __launch_bounds__(256, 2) void tail_fused(
    const unsigned short* __restrict__ ctx, const unsigned short* __restrict__ wo,
    const float* __restrict__ b_out, float* __restrict__ out,
    const unsigned short* __restrict__ qs, const unsigned short* __restrict__ ks,
    const float* __restrict__ c_s, float* __restrict__ attn_avg) {
  __shared__ __align__(16) unsigned short lds[3 * 8192];
  const int id = blockIdx.x;
  if (id < 512) {
    gemm_body(lds, ctx, wo, EMBD, (id >> 4) * 128, (id & 15) * 128, EpiOut{b_out, out});
  } else {
    attn_avg_body(lds, qs, ks, c_s, attn_avg, id - 512);
  }
}

// ---------------------------------------------------------------------------
// Flash attention fwd v3. Grid: B*H*(SEQ/128) = 512 x 512thr, XCD swizzle,
// setprio on MFMA clusters, defer-max, log2-domain, vti pre-transposed V.
// ---------------------------------------------------------------------------
__global__ __launch_bounds__(512, 4) void flash_fwd(
    const unsigned short* __restrict__ qs, const unsigned short* __restrict__ ks,
    const unsigned short* __restrict__ vti, unsigned short* __restrict__ ctx,
    float* __restrict__ c_s) {
  __shared__ __align__(16) unsigned short smem[32768];  // 2 bufs x (K 16KB + V^T 16KB)
  const int tid = threadIdx.x, w = tid >> 6, lane = tid & 63;
  const int g = lane >> 4, lr = lane & 15;
  const int blk = ((int)blockIdx.x & 7) * ((int)gridDim.x >> 3) + ((int)blockIdx.x >> 3);
  const int qt = blk & 15, h = (blk >> 4) & 15, b = blk >> 8;
  const int q0 = qt * 128;
  const size_t bh = ((size_t)(b * NHEAD + h)) * SEQ * HDIM;

  const int qrow = q0 + w * 16 + lr;
  bf16x8 qf[4];
#pragma unroll
  for (int kk = 0; kk < 4; ++kk)
    qf[kk] = *(const bf16x8*)(qs + bh + (size_t)qrow * HDIM + kk * 32 + g * 8);

  float m_run = -1e30f, l_run = 0.f;
  f32x4 o[8] = {};

  auto stage = [&](int buf, int t) {
    unsigned short* kt = smem + buf * 16384;
    unsigned short* vt = kt + 8192;
    const int key0 = t * 64;
#pragma unroll
    for (int c = 0; c < 2; ++c) {
      const int chunk = w * 2 + c;
      const int key = chunk * 4 + (lane >> 4);
      const int slot = lane & 15;
      gload_lds16(ks + bh + (size_t)(key0 + key) * HDIM + ((slot ^ (key & 7)) * 8),
                  &kt[chunk * 512]);
    }
#pragma unroll
    for (int c = 0; c < 2; ++c) {
      const int chunk = w * 2 + c;
      const int d = chunk * 8 + (lane >> 3);
      const int slot = lane & 7;
      gload_lds16(vti + bh + (size_t)d * SEQ + key0 + ((slot ^ (d & 7)) * 8),
                  &vt[chunk * 512]);
    }
  };

  stage(0, 0);
  asm volatile("s_waitcnt vmcnt(0)" ::: "memory");
  __syncthreads();
  int cur = 0;

  for (int t = 0; t < 32; ++t) {
    if (t + 1 < 32) stage(cur ^ 1, t + 1);
    const unsigned short* kt = smem + cur * 16384;
    const unsigned short* vt = kt + 8192;

    f32x4 st[4] = {};
    __builtin_amdgcn_s_setprio(1);
#pragma unroll
    for (int kk = 0; kk < 4; ++kk)
#pragma unroll
      for (int fc = 0; fc < 4; ++fc) {
        const int key = fc * 16 + lr;
        bf16x8 kf = *(const bf16x8*)&kt[key * 128 + (((kk * 4 + g) ^ (key & 7)) << 3)];
        st[fc] = __builtin_amdgcn_mfma_f32_16x16x32_bf16(kf, qf[kk], st[fc], 0, 0, 0);
      }
    __builtin_amdgcn_s_setprio(0);

    float tmax = st[0][0];
#pragma unroll
    for (int fc = 0; fc < 4; ++fc)
#pragma unroll
      for (int j = 0; j < 4; ++j) tmax = fmaxf(tmax, st[fc][j]);
    tmax = fmaxf(tmax, __shfl_xor(tmax, 16));
    tmax = fmaxf(tmax, __shfl_xor(tmax, 32));
    if (!__all(tmax <= m_run + 8.f)) {
      const float m_new = fmaxf(m_run, tmax);
      const float corr = __builtin_exp2f(m_run - m_new);
      l_run *= corr;
#pragma unroll
      for (int fd = 0; fd < 8; ++fd)
#pragma unroll
        for (int j = 0; j < 4; ++j) o[fd][j] *= corr;
      m_run = m_new;
    }
    float pt[4][4];
    float tsum = 0.f;
#pragma unroll
    for (int fc = 0; fc < 4; ++fc)
#pragma unroll
      for (int j = 0; j < 4; ++j) {
        const float e = __builtin_exp2f(st[fc][j] - m_run);
        pt[fc][j] = e; tsum += e;
      }
    tsum += __shfl_xor(tsum, 16);
    tsum += __shfl_xor(tsum, 32);
    l_run += tsum;

    bf16x8 pb[2];
#pragma unroll
    for (int c = 0; c < 2; ++c)
#pragma unroll
      for (int j = 0; j < 4; ++j) {
        pb[c][j]     = f2bfs(pt[2 * c][j]);
        pb[c][4 + j] = f2bfs(pt[2 * c + 1][j]);
      }

    __builtin_amdgcn_s_setprio(1);
#pragma unroll
    for (int fd = 0; fd < 8; ++fd) {
      const int d = fd * 16 + lr;
#pragma unroll
      for (int c = 0; c < 2; ++c) {
        bf16x8 vf = *(const bf16x8*)&vt[d * 64 + (((c * 4 + g) ^ (d & 7)) << 3)];
        o[fd] = __builtin_amdgcn_mfma_f32_16x16x32_bf16(vf, pb[c], o[fd], 0, 0, 0);
      }
    }
    __builtin_amdgcn_s_setprio(0);

    asm volatile("s_waitcnt vmcnt(0)" ::: "memory");
    __syncthreads();
    cur ^= 1;
  }

  const float inv_l = 1.0f / l_run;
  unsigned short* trp = smem + w * 2176;
#pragma unroll
  for (int fd = 0; fd < 8; ++fd)
#pragma unroll
    for (int jp = 0; jp < 2; ++jp) {
      const int d = fd * 16 + 4 * g + 2 * jp;
      unsigned valu = (unsigned)(unsigned short)f2bfs(o[fd][2 * jp] * inv_l) |
                      ((unsigned)(unsigned short)f2bfs(o[fd][2 * jp + 1] * inv_l) << 16);
      *(unsigned*)((char*)trp + lr * 272 + d * 2) = valu;
    }
  __syncthreads();
#pragma unroll
  for (int r4 = 0; r4 < 4; ++r4) {
    const int row = r4 * 4 + g;
    bf16x8 valv = *(const bf16x8*)((char*)trp + row * 272 + lr * 16);
    *(bf16x8*)(ctx + (size_t)(b * SEQ + q0 + w * 16 + row) * EMBD + h * HDIM + lr * 8) = valv;
  }
  if (g == 0) {
    const int ridx = (b * NHEAD + h) * SEQ + q0 + w * 16 + lr;
    c_s[ridx] = m_run + __log2f(l_run) + 4.0f;
  }
}

// ---------------------------------------------------------------------------
extern "C" void kernel_launch(void* const* d_in, const int* in_sizes, int n_in,
                              void* d_out, int out_size, void* d_ws, size_t ws_size,
                              hipStream_t stream) {
  const float* query = (const float*)d_in[0];
  // d_in[1] (key), d_in[2] (value) are ignored by the reference module
  const float* W_in  = (const float*)d_in[3];
  const float* b_in  = (const float*)d_in[4];
  const float* W_out = (const float*)d_in[5];
  const float* b_out = (const float*)d_in[6];

  float* out      = (float*)d_out;                       // [B,L,E]
  float* attn_avg = out + (size_t)BATCH * SEQ * EMBD;    // [B,L,L]

  char* ws = (char*)d_ws;
  auto take = [&](size_t bytes) { char* p = ws; ws += bytes; return p; };
  const size_t szBLE = (size_t)BATCH * SEQ * EMBD * 2;   // bf16 [B*L, E]
  unsigned short* qbf = (unsigned short*)take(szBLE);
  unsigned short* wi  = (unsigned short*)take((size_t)3 * EMBD * EMBD * 2);
  unsigned short* wo  = (unsigned short*)take((size_t)EMBD * EMBD * 2);
  unsigned short* qsb = (unsigned short*)take(szBLE);    // [B,H,L,D] *QSCALE
  unsigned short* ksb = (unsigned short*)take(szBLE);    // [B,H,L,D]
  unsigned short* vti = (unsigned short*)take(szBLE);    // [B,H,D,Lperm]
  unsigned short* ctx = (unsigned short*)take(szBLE);    // [B,L,H,D] == [B*L, E]
  float* c_s = (float*)take((size_t)BATCH * NHEAD * SEQ * 4);

  // cast query + W_in (W_out is cast by gemm_qkv8's trailing blocks)
  cvt_bf16_2<<<2048, 256, 0, stream>>>(query, qbf, BATCH * SEQ * EMBD,
                                       W_in, wi, 3 * EMBD * EMBD);

  // qkv = query @ W_in^T + b_in  (M=4096, N=6144, K=2048), 8-phase 256^2;
  // +32 trailing blocks cast W_out on the idle half-round
  gemm_qkv8<<<16 * 24 + 32, 512, 0, stream>>>(qbf, wi, W_out, wo,
                                              EpiQKV{b_in, qsb, ksb, vti});
  // attention (writes ctx, c_s)
  flash_fwd<<<BATCH * NHEAD * (SEQ / 128), 512, 0, stream>>>(qsb, ksb, vti, ctx, c_s);
  // fused tail: output GEMM (blocks 0-511) + attn_avg (512-1023)
  tail_fused<<<1024, 256, 0, stream>>>(ctx, wo, b_out, out, qsb, ksb, c_s, attn_avg);
}